// Round 7
// baseline (526.200 us; speedup 1.0000x reference)
//
#include <hip/hip_runtime.h>
#include <math.h>

#define NN   65536      // total nodes
#define NPER 1024       // nodes per graph
#define NE   1048576    // edges
#define NB   64         // graphs

// ---------------- CSR build ----------------

__global__ __launch_bounds__(256) void count_kernel(const int* __restrict__ ei, int* __restrict__ cnt){
  int e = blockIdx.x*256 + threadIdx.x;
  if (e < NE) atomicAdd(&cnt[ei[NE + e]], 1);
}

// hierarchical exclusive scan of cnt[NN] -> off[NN+1] (+ cursor copy)
__global__ __launch_bounds__(1024) void scan1_kernel(const int* __restrict__ cnt,
      int* __restrict__ loc, int* __restrict__ bsum){
  __shared__ int wsum[16];
  int t = threadIdx.x;
  int i = blockIdx.x*1024 + t;
  int lane = t & 63, wid = t >> 6;
  int v = cnt[i];
  int s = v;
  #pragma unroll
  for (int d = 1; d < 64; d <<= 1){
    int src = (lane >= d) ? (lane - d) : lane;
    int u = __shfl(s, src);
    if (lane >= d) s += u;
  }
  if (lane == 63) wsum[wid] = s;
  __syncthreads();
  if (wid == 0){
    int ws = (lane < 16) ? wsum[lane] : 0;
    #pragma unroll
    for (int d = 1; d < 16; d <<= 1){
      int src = (lane >= d) ? (lane - d) : lane;
      int u = __shfl(ws, src);
      if (lane >= d) ws += u;
    }
    if (lane < 16) wsum[lane] = ws;
  }
  __syncthreads();
  int base = (wid > 0) ? wsum[wid - 1] : 0;
  loc[i] = base + s - v;                 // exclusive within block
  if (t == 1023) bsum[blockIdx.x] = base + s;
}

__global__ __launch_bounds__(64) void scan2_kernel(const int* __restrict__ bsum, int* __restrict__ boff){
  int t = threadIdx.x;
  int v = bsum[t];
  int s = v;
  #pragma unroll
  for (int d = 1; d < 64; d <<= 1){
    int src = (t >= d) ? (t - d) : t;
    int u = __shfl(s, src);
    if (t >= d) s += u;
  }
  boff[t] = s - v;
}

__global__ __launch_bounds__(1024) void scan3_kernel(const int* __restrict__ loc, const int* __restrict__ boff,
      int* __restrict__ off, int* __restrict__ cursor){
  int i = blockIdx.x*1024 + threadIdx.x;
  int v = loc[i] + boff[blockIdx.x];
  off[i] = v;
  cursor[i] = v;
  if (i == NN - 1) off[NN] = NE;
}

__global__ __launch_bounds__(256) void fill_kernel(const int* __restrict__ ei, int* cursor, int* __restrict__ adj){
  int e = blockIdx.x*256 + threadIdx.x;
  if (e < NE){
    int pos = atomicAdd(&cursor[ei[NE + e]], 1);
    adj[pos] = ei[e];
  }
}

// ---------------- aggregation (segment_sum of x[src] into dst rows) ----------------
// one wave per node, float4 per lane, 8 row-loads in flight, XCD-chunked swizzle.

__global__ __launch_bounds__(256) void gather_kernel(const float* __restrict__ x, int stride, int F,
      const int* __restrict__ off, const int* __restrict__ adj, float* __restrict__ agg,
      const int* __restrict__ alive){
  int bid = blockIdx.x;
  bid = (bid & 7) * (gridDim.x >> 3) + (bid >> 3);   // round-robin XCD -> contiguous chunks
  int w = (bid*256 + (int)threadIdx.x) >> 6;
  int lane = threadIdx.x & 63;
  if (w >= NN) return;
  if (alive && !alive[w]) return;
  int s0 = off[w], s1 = off[w+1];
  if (F == 64){
    int sub = lane >> 4;            // edge-group 0..3
    int fl  = (lane & 15) * 4;      // features fl..fl+3
    float4 a0 = {0,0,0,0}, a1 = {0,0,0,0};
    for (int e = s0; e < s1; e += 8){
      int e0 = e + sub, e1 = e + 4 + sub;
      if (e0 < s1){
        float4 v = *(const float4*)&x[(size_t)adj[e0]*stride + fl];
        a0.x += v.x; a0.y += v.y; a0.z += v.z; a0.w += v.w;
      }
      if (e1 < s1){
        float4 v = *(const float4*)&x[(size_t)adj[e1]*stride + fl];
        a1.x += v.x; a1.y += v.y; a1.z += v.z; a1.w += v.w;
      }
    }
    a0.x += a1.x; a0.y += a1.y; a0.z += a1.z; a0.w += a1.w;
    #pragma unroll
    for (int m = 16; m <= 32; m <<= 1){
      a0.x += __shfl_xor(a0.x, m);
      a0.y += __shfl_xor(a0.y, m);
      a0.z += __shfl_xor(a0.z, m);
      a0.w += __shfl_xor(a0.w, m);
    }
    if (lane < 16) *(float4*)&agg[(size_t)w*128 + fl] = a0;
  } else {
    int sub = lane >> 5;            // edge-group 0..1
    int fl  = (lane & 31) * 4;
    float4 a0 = {0,0,0,0}, a1 = {0,0,0,0}, a2 = {0,0,0,0}, a3 = {0,0,0,0};
    for (int e = s0; e < s1; e += 8){
      int e0 = e + sub, e1 = e + 2 + sub, e2 = e + 4 + sub, e3 = e + 6 + sub;
      if (e0 < s1){
        float4 v = *(const float4*)&x[(size_t)adj[e0]*stride + fl];
        a0.x += v.x; a0.y += v.y; a0.z += v.z; a0.w += v.w;
      }
      if (e1 < s1){
        float4 v = *(const float4*)&x[(size_t)adj[e1]*stride + fl];
        a1.x += v.x; a1.y += v.y; a1.z += v.z; a1.w += v.w;
      }
      if (e2 < s1){
        float4 v = *(const float4*)&x[(size_t)adj[e2]*stride + fl];
        a2.x += v.x; a2.y += v.y; a2.z += v.z; a2.w += v.w;
      }
      if (e3 < s1){
        float4 v = *(const float4*)&x[(size_t)adj[e3]*stride + fl];
        a3.x += v.x; a3.y += v.y; a3.z += v.z; a3.w += v.w;
      }
    }
    a0.x += a1.x + a2.x + a3.x;
    a0.y += a1.y + a2.y + a3.y;
    a0.z += a1.z + a2.z + a3.z;
    a0.w += a1.w + a2.w + a3.w;
    a0.x += __shfl_xor(a0.x, 32);
    a0.y += __shfl_xor(a0.y, 32);
    a0.z += __shfl_xor(a0.z, 32);
    a0.w += __shfl_xor(a0.w, 32);
    if (lane < 32) *(float4*)&agg[(size_t)w*128 + fl] = a0;
  }
}

// ---------------- conv: y = relu(x@Wr + agg@Wn + b), fused raw score = y . p ----------------
// 128x128 tile, 256 threads, 8x8 per thread, double-buffered LDS (one barrier/tile):
// commit tile t+1 into buf[cur^1] while computing tile t from buf[cur];
// explicit 2-stage k-register-pipeline (named regs, fully static indexing).
// xsT XOR-swizzle: phys row-quad = (rq&24)|((rq+kq)&7), conflict-free both sides.
// NOTE: yout aliases aggb: every wave's last aggb prefetch is vmcnt-drained at its
// final commit, which precedes the last barrier; epilogue writes come after.

#define LOADK(KK, X0, X1, W0, W1) do {                                   \
    const int physr_ = (rb & 24) | ((rb + ((KK) >> 2)) & 7);             \
    X0 = *(const float4*)&xs[(KK)*128 + physr_*4];                       \
    X1 = *(const float4*)&xs[(KK)*128 + physr_*4 + 64];                  \
    W0 = *(const float4*)&ws[(KK)*128 + clo];                            \
    W1 = *(const float4*)&ws[(KK)*128 + clo + 64];                       \
  } while(0)

#define FMA8(X0, X1, W0, W1) do {                                        \
    const float* xe0 = (const float*)&(X0);                              \
    const float* xe1 = (const float*)&(X1);                              \
    const float* we0 = (const float*)&(W0);                              \
    const float* we1 = (const float*)&(W1);                              \
    _Pragma("unroll")                                                    \
    for (int r = 0; r < 4; ++r){                                         \
      float a0 = xe0[r], a1 = xe1[r];                                    \
      _Pragma("unroll")                                                  \
      for (int c = 0; c < 4; ++c){                                       \
        acc[0][0][r][c] = fmaf(a0, we0[c], acc[0][0][r][c]);             \
        acc[0][1][r][c] = fmaf(a0, we1[c], acc[0][1][r][c]);             \
        acc[1][0][r][c] = fmaf(a1, we0[c], acc[1][0][r][c]);             \
        acc[1][1][r][c] = fmaf(a1, we1[c], acc[1][1][r][c]);             \
      }                                                                  \
    }                                                                    \
  } while(0)

__global__ __launch_bounds__(256, 2) void conv_kernel(const float* __restrict__ xsrc, int strideX, int Kx,
      const float* __restrict__ Wr, const float* aggb, int Ka, const float* __restrict__ Wn,
      const float* __restrict__ bias, const float* __restrict__ p,
      float* yout, float* __restrict__ score){
  __shared__ float xsT[2][32*128];   // [buf][kk][swizzled row]
  __shared__ float wsS[2][32*128];   // [buf][kk][col]
  const int tid = threadIdx.x;
  const int row0 = blockIdx.x * 128;
  const int rq  = tid >> 3;        // staging: row-quad 0..31
  const int kq  = tid & 7;         // staging: k-quad 0..7
  const int physw = (rq & 24) | ((rq + kq) & 7);   // swizzled write block
  const int rb  = tid >> 4;        // compute: row block 0..15 (rows rb*4.., +64)
  const int clo = (tid & 15) * 4;  // compute cols clo..+3, clo+64..+67

  float acc[2][2][4][4];
  #pragma unroll
  for (int i = 0; i < 2; ++i)
    #pragma unroll
    for (int j = 0; j < 2; ++j)
      #pragma unroll
      for (int r = 0; r < 4; ++r)
        #pragma unroll
        for (int c = 0; c < 4; ++c) acc[i][j][r][c] = 0.f;

  const int nt0 = Kx >> 5, nt = nt0 + (Ka >> 5);
  float4 xr0, xr1, xr2, xr3, wq0, wq1, wq2, wq3;

  auto prefetch = [&](int t){
    const float* X; int stride; const float* W; int kc;
    if (t < nt0){ X = xsrc; stride = strideX; W = Wr;  kc = t*32; }
    else        { X = aggb; stride = 128;     W = Wn;  kc = (t - nt0)*32; }
    const float* xp = X + (size_t)(row0 + rq*4)*stride + kc + kq*4;
    xr0 = *(const float4*)(xp);
    xr1 = *(const float4*)(xp + stride);
    xr2 = *(const float4*)(xp + 2*stride);
    xr3 = *(const float4*)(xp + 3*stride);
    const float* wp = W + (size_t)kc*128 + (tid >> 5)*128 + (tid & 31)*4;
    wq0 = *(const float4*)(wp);
    wq1 = *(const float4*)(wp + 8*128);
    wq2 = *(const float4*)(wp + 16*128);
    wq3 = *(const float4*)(wp + 24*128);
  };

  auto commit = [&](int sel){
    const float* x0 = (const float*)&xr0;
    const float* x1 = (const float*)&xr1;
    const float* x2 = (const float*)&xr2;
    const float* x3 = (const float*)&xr3;
    #pragma unroll
    for (int c = 0; c < 4; ++c)
      *(float4*)&xsT[sel][(kq*4 + c)*128 + physw*4] = make_float4(x0[c], x1[c], x2[c], x3[c]);
    float* wpS = &wsS[sel][(tid >> 5)*128 + (tid & 31)*4];
    *(float4*)(wpS)          = wq0;
    *(float4*)(wpS + 8*128)  = wq1;
    *(float4*)(wpS + 16*128) = wq2;
    *(float4*)(wpS + 24*128) = wq3;
  };

  prefetch(0);
  commit(0);
  if (nt > 1) prefetch(1);
  __syncthreads();

  for (int t = 0; t < nt; ++t){
    const int cur = t & 1;
    if (t + 1 < nt){
      commit(cur ^ 1);                 // regs hold tile t+1 (vmcnt drained here)
      if (t + 2 < nt) prefetch(t + 2); // global loads fly under compute
    }
    const float* xs = &xsT[cur][0];
    const float* ws = &wsS[cur][0];
    {
      float4 xa0, xa1, wa0, wa1, xb0, xb1, wb0, wb1;
      LOADK(0, xa0, xa1, wa0, wa1);
      #pragma unroll
      for (int kk = 0; kk < 32; kk += 2){
        LOADK(kk + 1, xb0, xb1, wb0, wb1);
        FMA8(xa0, xa1, wa0, wa1);
        if (kk + 2 < 32) LOADK(kk + 2, xa0, xa1, wa0, wa1);
        FMA8(xb0, xb1, wb0, wb1);
      }
    }
    __syncthreads();
  }

  float4 bv0 = *(const float4*)&bias[clo];
  float4 bv1 = *(const float4*)&bias[clo + 64];
  float4 pv0 = *(const float4*)&p[clo];
  float4 pv1 = *(const float4*)&p[clo + 64];
  const float* bvp[2] = {(const float*)&bv0, (const float*)&bv1};
  const float* pvp[2] = {(const float*)&pv0, (const float*)&pv1};
  #pragma unroll
  for (int i = 0; i < 2; ++i)
    #pragma unroll
    for (int r = 0; r < 4; ++r){
      int row = row0 + rb*4 + i*64 + r;
      float part = 0.f;
      #pragma unroll
      for (int j = 0; j < 2; ++j){
        float4 o;
        o.x = fmaxf(acc[i][j][r][0] + bvp[j][0], 0.f);
        o.y = fmaxf(acc[i][j][r][1] + bvp[j][1], 0.f);
        o.z = fmaxf(acc[i][j][r][2] + bvp[j][2], 0.f);
        o.w = fmaxf(acc[i][j][r][3] + bvp[j][3], 0.f);
        *(float4*)&yout[(size_t)row*128 + clo + j*64] = o;
        part += o.x*pvp[j][0] + o.y*pvp[j][1] + o.z*pvp[j][2] + o.w*pvp[j][3];
      }
      #pragma unroll
      for (int m = 8; m >= 1; m >>= 1) part += __shfl_xor(part, m);
      if ((tid & 15) == 0) score[row] = part;
    }
}

// ---------------- per-graph top-k via bitonic sort of (raw score desc, idx asc) ----------------
// ordering is invariant to the positive scale 1/||p||; apply it only inside tanh.

__global__ __launch_bounds__(1024) void topk_kernel(const float* __restrict__ score, const int* __restrict__ alive_cur,
      int* __restrict__ alive_next, float* __restrict__ tanhv, const float* __restrict__ p, int m){
  __shared__ float sv[1024];
  __shared__ int   si[1024];
  __shared__ float rnorm;
  int g = blockIdx.x, t = threadIdx.x;
  if (t < 64){
    float v0 = p[t], v1 = p[t + 64];
    float ss = v0*v0 + v1*v1;
    #pragma unroll
    for (int mm = 32; mm >= 1; mm >>= 1) ss += __shfl_xor(ss, mm);
    if (t == 0) rnorm = rsqrtf(ss);
  }
  int node = g*NPER + t;
  bool ok = alive_cur ? (alive_cur[node] != 0) : true;
  sv[t] = ok ? score[node] : -INFINITY;
  si[t] = node;
  alive_next[node] = 0;
  __syncthreads();
  for (int size = 2; size <= 1024; size <<= 1){
    for (int stride = size >> 1; stride > 0; stride >>= 1){
      int j = t ^ stride;
      if (j > t){
        float vt = sv[t], vj = sv[j];
        int   it = si[t], ij = si[j];
        bool beforeTJ = (vt > vj) || (vt == vj && it < ij);  // t belongs first
        bool ascending = ((t & size) == 0);
        bool dosw = ascending ? !beforeTJ : beforeTJ;
        if (dosw){ sv[t] = vj; sv[j] = vt; si[t] = ij; si[j] = it; }
      }
      __syncthreads();
    }
  }
  if (t < m){
    int idx = si[t];
    alive_next[idx] = 1;
    tanhv[idx] = tanhf(sv[t] * rnorm);
  }
}

// ---------------- fused: x = selected ? y*tanh(s) : 0  +  per-graph masked max/mean readout ----------------

__global__ __launch_bounds__(1024) void apply_readout_kernel(const float* __restrict__ y,
      const int* __restrict__ alive, const float* __restrict__ tanhv,
      float* __restrict__ x, float* __restrict__ h, int m){
  __shared__ float smx[32][33];
  __shared__ float ssm[32][33];
  int g = blockIdx.x;
  int fq = blockIdx.y;
  int t = threadIdx.x;
  int c  = t >> 5;         // node group 0..31
  int lf = t & 31;         // feature within quarter
  int f  = fq*32 + lf;
  int base = g*NPER;
  float mx = -INFINITY, sm = 0.f;
  #pragma unroll 4
  for (int i = 0; i < 32; ++i){
    int node = base + c + i*32;
    int al = alive[node];
    float tv = tanhv[node];           // garbage for dead nodes, never used
    float v = y[(size_t)node*128 + f];
    float o = al ? v*tv : 0.f;
    x[(size_t)node*128 + f] = o;
    mx = al ? fmaxf(mx, o) : mx;
    sm += o;
  }
  smx[c][lf] = mx; ssm[c][lf] = sm;
  __syncthreads();
  for (int s = 16; s > 0; s >>= 1){
    if (c < s){
      smx[c][lf] = fmaxf(smx[c][lf], smx[c+s][lf]);
      ssm[c][lf] += ssm[c+s][lf];
    }
    __syncthreads();
  }
  if (c == 0){
    h[g*256 + f]       += smx[0][lf];
    h[g*256 + 128 + f] += ssm[0][lf] / (float)m;
  }
}

// ---------------- final MLP + log_softmax ----------------

__global__ __launch_bounds__(128) void final_kernel(const float* __restrict__ h,
      const float* __restrict__ l1w, const float* __restrict__ l1b,
      const float* __restrict__ l2w, const float* __restrict__ l2b,
      float* __restrict__ out){
  int g = blockIdx.x, t = threadIdx.x;
  __shared__ float hrow[256];
  __shared__ float red0[128], red1[128];
  hrow[t]       = h[g*256 + t];
  hrow[t + 128] = h[g*256 + 128 + t];
  __syncthreads();
  float a = l1b[t];
  for (int k = 0; k < 256; ++k) a = fmaf(hrow[k], l1w[k*128 + t], a);
  a = fmaxf(a, 0.f);
  red0[t] = a * l2w[t*2 + 0];
  red1[t] = a * l2w[t*2 + 1];
  __syncthreads();
  for (int s = 64; s > 0; s >>= 1){
    if (t < s){ red0[t] += red0[t + s]; red1[t] += red1[t + s]; }
    __syncthreads();
  }
  if (t == 0){
    float z0 = fmaxf(red0[0] + l2b[0], 0.f);
    float z1 = fmaxf(red1[0] + l2b[1], 0.f);
    float mz = fmaxf(z0, z1);
    float lse = mz + logf(expf(z0 - mz) + expf(z1 - mz));
    out[g*2 + 0] = z0 - lse;
    out[g*2 + 1] = z1 - lse;
  }
}

// ---------------- host ----------------

static inline size_t alignup(size_t x){ return (x + 255) & ~(size_t)255; }

extern "C" void kernel_launch(void* const* d_in, const int* in_sizes, int n_in,
                              void* d_out, int out_size, void* d_ws, size_t ws_size,
                              hipStream_t stream) {
  const float* x_in = (const float*)d_in[0];
  const int*   ei   = (const int*)d_in[1];
  const float* Wr[3] = {(const float*)d_in[3], (const float*)d_in[6], (const float*)d_in[9]};
  const float* Wn[3] = {(const float*)d_in[4], (const float*)d_in[7], (const float*)d_in[10]};
  const float* bs[3] = {(const float*)d_in[5], (const float*)d_in[8], (const float*)d_in[11]};
  const float* ps[3] = {(const float*)d_in[12], (const float*)d_in[13], (const float*)d_in[14]};
  const float* l1w = (const float*)d_in[15];
  const float* l1b = (const float*)d_in[16];
  const float* l2w = (const float*)d_in[17];
  const float* l2b = (const float*)d_in[18];
  float* out = (float*)d_out;

  char* w = (char*)d_ws;
  size_t o = 0;
  auto take = [&](size_t bytes) -> void* { void* p = w + o; o = alignup(o + bytes); return p; };
  int*   off    = (int*)  take((size_t)(NN + 1) * 4);
  int*   adj    = (int*)  take((size_t)NE * 4);
  int*   cnt    = (int*)  take((size_t)NN * 4);
  int*   loc    = (int*)  take((size_t)NN * 4);
  int*   cursor = (int*)  take((size_t)NN * 4);
  int*   bsum   = (int*)  take(64 * 4);
  int*   boff   = (int*)  take(64 * 4);
  int*   aliveA = (int*)  take((size_t)NN * 4);
  int*   aliveB = (int*)  take((size_t)NN * 4);
  float* tanhv  = (float*)take((size_t)NN * 4);
  float* score  = (float*)take((size_t)NN * 4);
  float* h      = (float*)take((size_t)NB * 256 * 4);
  float* A      = (float*)take((size_t)NN * 128 * 4);  // node features (current level)
  float* Bb     = (float*)take((size_t)NN * 128 * 4);  // agg, then conv output y
  (void)ws_size; (void)n_in; (void)in_sizes; (void)out_size;

  // CSR build (by dst, storing src)
  hipMemsetAsync(cnt, 0, (size_t)NN * 4, stream);
  count_kernel<<<NE/256, 256, 0, stream>>>(ei, cnt);
  scan1_kernel<<<NN/1024, 1024, 0, stream>>>(cnt, loc, bsum);
  scan2_kernel<<<1, 64, 0, stream>>>(bsum, boff);
  scan3_kernel<<<NN/1024, 1024, 0, stream>>>(loc, boff, off, cursor);
  fill_kernel<<<NE/256, 256, 0, stream>>>(ei, cursor, adj);
  hipMemsetAsync(h, 0, (size_t)NB * 256 * 4, stream);

  const int MS[3] = {820, 656, 525};
  int* aliveCur = nullptr;
  int* aliveNext = aliveA;
  for (int l = 0; l < 3; ++l){
    if (l == 0){
      gather_kernel<<<NN*64/256, 256, 0, stream>>>(x_in, 64, 64, off, adj, Bb, nullptr);
      conv_kernel<<<NN/128, 256, 0, stream>>>(x_in, 64, 64, Wr[0], Bb, 64, Wn[0], bs[0], ps[0], Bb, score);
    } else {
      gather_kernel<<<NN*64/256, 256, 0, stream>>>(A, 128, 128, off, adj, Bb, aliveCur);
      conv_kernel<<<NN/128, 256, 0, stream>>>(A, 128, 128, Wr[l], Bb, 128, Wn[l], bs[l], ps[l], Bb, score);
    }
    topk_kernel<<<NB, 1024, 0, stream>>>(score, aliveCur, aliveNext, tanhv, ps[l], MS[l]);
    apply_readout_kernel<<<dim3(NB, 4), 1024, 0, stream>>>(Bb, aliveNext, tanhv, A, h, MS[l]);
    aliveCur = aliveNext;
    aliveNext = (l == 0) ? aliveB : aliveA;
  }
  final_kernel<<<NB, 128, 0, stream>>>(h, l1w, l1b, l2w, l2b, out);
}

// Round 8
// 454.322 us; speedup vs baseline: 1.1582x; 1.1582x over previous
//
#include <hip/hip_runtime.h>
#include <math.h>

#define NN   65536      // total nodes
#define NPER 1024       // nodes per graph
#define NE   1048576    // edges
#define NB   64         // graphs

// ---------------- CSR build ----------------

__global__ __launch_bounds__(256) void count_kernel(const int* __restrict__ ei, int* __restrict__ cnt){
  int e = blockIdx.x*256 + threadIdx.x;
  if (e < NE) atomicAdd(&cnt[ei[NE + e]], 1);
}

// hierarchical exclusive scan of cnt[NN] -> off[NN+1] (+ cursor copy)
__global__ __launch_bounds__(1024) void scan1_kernel(const int* __restrict__ cnt,
      int* __restrict__ loc, int* __restrict__ bsum){
  __shared__ int wsum[16];
  int t = threadIdx.x;
  int i = blockIdx.x*1024 + t;
  int lane = t & 63, wid = t >> 6;
  int v = cnt[i];
  int s = v;
  #pragma unroll
  for (int d = 1; d < 64; d <<= 1){
    int src = (lane >= d) ? (lane - d) : lane;
    int u = __shfl(s, src);
    if (lane >= d) s += u;
  }
  if (lane == 63) wsum[wid] = s;
  __syncthreads();
  if (wid == 0){
    int ws = (lane < 16) ? wsum[lane] : 0;
    #pragma unroll
    for (int d = 1; d < 16; d <<= 1){
      int src = (lane >= d) ? (lane - d) : lane;
      int u = __shfl(ws, src);
      if (lane >= d) ws += u;
    }
    if (lane < 16) wsum[lane] = ws;
  }
  __syncthreads();
  int base = (wid > 0) ? wsum[wid - 1] : 0;
  loc[i] = base + s - v;                 // exclusive within block
  if (t == 1023) bsum[blockIdx.x] = base + s;
}

__global__ __launch_bounds__(64) void scan2_kernel(const int* __restrict__ bsum, int* __restrict__ boff){
  int t = threadIdx.x;
  int v = bsum[t];
  int s = v;
  #pragma unroll
  for (int d = 1; d < 64; d <<= 1){
    int src = (t >= d) ? (t - d) : t;
    int u = __shfl(s, src);
    if (t >= d) s += u;
  }
  boff[t] = s - v;
}

__global__ __launch_bounds__(1024) void scan3_kernel(const int* __restrict__ loc, const int* __restrict__ boff,
      int* __restrict__ off, int* __restrict__ cursor){
  int i = blockIdx.x*1024 + threadIdx.x;
  int v = loc[i] + boff[blockIdx.x];
  off[i] = v;
  cursor[i] = v;
  if (i == NN - 1) off[NN] = NE;
}

__global__ __launch_bounds__(256) void fill_kernel(const int* __restrict__ ei, int* cursor, int* __restrict__ adj){
  int e = blockIdx.x*256 + threadIdx.x;
  if (e < NE){
    int pos = atomicAdd(&cursor[ei[NE + e]], 1);
    adj[pos] = ei[e];
  }
}

// ---------------- aggregation (segment_sum of x[src] into dst rows) ----------------
// one wave per node, float4 per lane, 8 row-loads in flight, XCD-chunked swizzle.

__global__ __launch_bounds__(256) void gather_kernel(const float* __restrict__ x, int stride, int F,
      const int* __restrict__ off, const int* __restrict__ adj, float* __restrict__ agg,
      const int* __restrict__ alive){
  int bid = blockIdx.x;
  bid = (bid & 7) * (gridDim.x >> 3) + (bid >> 3);   // round-robin XCD -> contiguous chunks
  int w = (bid*256 + (int)threadIdx.x) >> 6;
  int lane = threadIdx.x & 63;
  if (w >= NN) return;
  if (alive && !alive[w]) return;
  int s0 = off[w], s1 = off[w+1];
  if (F == 64){
    int sub = lane >> 4;            // edge-group 0..3
    int fl  = (lane & 15) * 4;      // features fl..fl+3
    float4 a0 = {0,0,0,0}, a1 = {0,0,0,0};
    for (int e = s0; e < s1; e += 8){
      int e0 = e + sub, e1 = e + 4 + sub;
      if (e0 < s1){
        float4 v = *(const float4*)&x[(size_t)adj[e0]*stride + fl];
        a0.x += v.x; a0.y += v.y; a0.z += v.z; a0.w += v.w;
      }
      if (e1 < s1){
        float4 v = *(const float4*)&x[(size_t)adj[e1]*stride + fl];
        a1.x += v.x; a1.y += v.y; a1.z += v.z; a1.w += v.w;
      }
    }
    a0.x += a1.x; a0.y += a1.y; a0.z += a1.z; a0.w += a1.w;
    #pragma unroll
    for (int m = 16; m <= 32; m <<= 1){
      a0.x += __shfl_xor(a0.x, m);
      a0.y += __shfl_xor(a0.y, m);
      a0.z += __shfl_xor(a0.z, m);
      a0.w += __shfl_xor(a0.w, m);
    }
    if (lane < 16) *(float4*)&agg[(size_t)w*128 + fl] = a0;
  } else {
    int sub = lane >> 5;            // edge-group 0..1
    int fl  = (lane & 31) * 4;
    float4 a0 = {0,0,0,0}, a1 = {0,0,0,0}, a2 = {0,0,0,0}, a3 = {0,0,0,0};
    for (int e = s0; e < s1; e += 8){
      int e0 = e + sub, e1 = e + 2 + sub, e2 = e + 4 + sub, e3 = e + 6 + sub;
      if (e0 < s1){
        float4 v = *(const float4*)&x[(size_t)adj[e0]*stride + fl];
        a0.x += v.x; a0.y += v.y; a0.z += v.z; a0.w += v.w;
      }
      if (e1 < s1){
        float4 v = *(const float4*)&x[(size_t)adj[e1]*stride + fl];
        a1.x += v.x; a1.y += v.y; a1.z += v.z; a1.w += v.w;
      }
      if (e2 < s1){
        float4 v = *(const float4*)&x[(size_t)adj[e2]*stride + fl];
        a2.x += v.x; a2.y += v.y; a2.z += v.z; a2.w += v.w;
      }
      if (e3 < s1){
        float4 v = *(const float4*)&x[(size_t)adj[e3]*stride + fl];
        a3.x += v.x; a3.y += v.y; a3.z += v.z; a3.w += v.w;
      }
    }
    a0.x += a1.x + a2.x + a3.x;
    a0.y += a1.y + a2.y + a3.y;
    a0.z += a1.z + a2.z + a3.z;
    a0.w += a1.w + a2.w + a3.w;
    a0.x += __shfl_xor(a0.x, 32);
    a0.y += __shfl_xor(a0.y, 32);
    a0.z += __shfl_xor(a0.z, 32);
    a0.w += __shfl_xor(a0.w, 32);
    if (lane < 32) *(float4*)&agg[(size_t)w*128 + fl] = a0;
  }
}

// ---------------- conv: y = relu(x@Wr + agg@Wn + b), fused raw score = y . p ----------------
// 128x128 tile, 512 threads (16 waves/CU at 2 blocks/CU), 4 rows x 8 cols per thread.
// Round-5 schedule (prefetch regs -> commit LDS -> compute, 2 barriers/tile), which
// measured 0 bank conflicts & no spills; R6's deeper reg pipeline spilled (192MB scratch).
// Staging role-split: threads 0-255 stage X (4x4 micro-transpose, XOR swizzle),
// threads 256-511 stage W. xsT phys row-quad = (rq&24)|((rq+kq)&7).
// NOTE: yout aliases aggb: all aggb reads complete before the last compute barrier;
// epilogue writes after.

__global__ __launch_bounds__(512) void conv_kernel(const float* __restrict__ xsrc, int strideX, int Kx,
      const float* __restrict__ Wr, const float* aggb, int Ka, const float* __restrict__ Wn,
      const float* __restrict__ bias, const float* __restrict__ p,
      float* yout, float* __restrict__ score){
  __shared__ float xsT[32*128];    // [kk][swizzled row]
  __shared__ float wsS[32*128];    // [kk][col]
  const int tid = threadIdx.x;
  const int row0 = blockIdx.x * 128;
  const bool stX = tid < 256;
  const int stid = tid & 255;
  const int rq  = stid >> 3;       // X staging: row-quad 0..31
  const int kq  = stid & 7;        // X staging: k-quad 0..7
  const int physw = (rq & 24) | ((rq + kq) & 7);   // swizzled write block
  const int rb  = tid >> 4;        // compute: row block 0..31 -> rows rb*4..+3
  const int clo = (tid & 15) * 4;  // compute cols clo..+3, clo+64..+67

  float acc[2][4][4];
  #pragma unroll
  for (int j = 0; j < 2; ++j)
    #pragma unroll
    for (int r = 0; r < 4; ++r)
      #pragma unroll
      for (int c = 0; c < 4; ++c) acc[j][r][c] = 0.f;

  const int nt0 = Kx >> 5, nt = nt0 + (Ka >> 5);
  float4 r0, r1, r2, r3;           // prefetch regs (X rows or W row-quads)

  auto prefetch = [&](int t){
    const float* X; int stride; const float* W; int kc;
    if (t < nt0){ X = xsrc; stride = strideX; W = Wr;  kc = t*32; }
    else        { X = aggb; stride = 128;     W = Wn;  kc = (t - nt0)*32; }
    if (stX){
      const float* xp = X + (size_t)(row0 + rq*4)*stride + kc + kq*4;
      r0 = *(const float4*)(xp);
      r1 = *(const float4*)(xp + stride);
      r2 = *(const float4*)(xp + 2*stride);
      r3 = *(const float4*)(xp + 3*stride);
    } else {
      const float* wp = W + (size_t)kc*128 + (stid >> 5)*128 + (stid & 31)*4;
      r0 = *(const float4*)(wp);
      r1 = *(const float4*)(wp + 8*128);
      r2 = *(const float4*)(wp + 16*128);
      r3 = *(const float4*)(wp + 24*128);
    }
  };

  auto commit = [&](){
    if (stX){
      const float* x0 = (const float*)&r0;
      const float* x1 = (const float*)&r1;
      const float* x2 = (const float*)&r2;
      const float* x3 = (const float*)&r3;
      #pragma unroll
      for (int c = 0; c < 4; ++c)
        *(float4*)&xsT[(kq*4 + c)*128 + physw*4] = make_float4(x0[c], x1[c], x2[c], x3[c]);
    } else {
      float* wpS = &wsS[(stid >> 5)*128 + (stid & 31)*4];
      *(float4*)(wpS)          = r0;
      *(float4*)(wpS + 8*128)  = r1;
      *(float4*)(wpS + 16*128) = r2;
      *(float4*)(wpS + 24*128) = r3;
    }
  };

  prefetch(0);
  for (int t = 0; t < nt; ++t){
    __syncthreads();               // previous tile's compute done, LDS reusable
    commit();
    __syncthreads();
    if (t + 1 < nt) prefetch(t + 1);   // global loads in flight during compute
    #pragma unroll 8
    for (int kk = 0; kk < 32; ++kk){
      const int physr = (rb & 24) | ((rb + (kk >> 2)) & 7);
      const float4 xv  = *(const float4*)&xsT[kk*128 + physr*4];
      const float4 wv0 = *(const float4*)&wsS[kk*128 + clo];
      const float4 wv1 = *(const float4*)&wsS[kk*128 + clo + 64];
      const float* xe  = (const float*)&xv;
      const float* we0 = (const float*)&wv0;
      const float* we1 = (const float*)&wv1;
      #pragma unroll
      for (int r = 0; r < 4; ++r){
        float a = xe[r];
        #pragma unroll
        for (int c = 0; c < 4; ++c){
          acc[0][r][c] = fmaf(a, we0[c], acc[0][r][c]);
          acc[1][r][c] = fmaf(a, we1[c], acc[1][r][c]);
        }
      }
    }
  }

  float4 bv0 = *(const float4*)&bias[clo];
  float4 bv1 = *(const float4*)&bias[clo + 64];
  float4 pv0 = *(const float4*)&p[clo];
  float4 pv1 = *(const float4*)&p[clo + 64];
  const float* bvp[2] = {(const float*)&bv0, (const float*)&bv1};
  const float* pvp[2] = {(const float*)&pv0, (const float*)&pv1};
  #pragma unroll
  for (int r = 0; r < 4; ++r){
    int row = row0 + rb*4 + r;
    float part = 0.f;
    #pragma unroll
    for (int j = 0; j < 2; ++j){
      float4 o;
      o.x = fmaxf(acc[j][r][0] + bvp[j][0], 0.f);
      o.y = fmaxf(acc[j][r][1] + bvp[j][1], 0.f);
      o.z = fmaxf(acc[j][r][2] + bvp[j][2], 0.f);
      o.w = fmaxf(acc[j][r][3] + bvp[j][3], 0.f);
      *(float4*)&yout[(size_t)row*128 + clo + j*64] = o;
      part += o.x*pvp[j][0] + o.y*pvp[j][1] + o.z*pvp[j][2] + o.w*pvp[j][3];
    }
    #pragma unroll
    for (int m = 8; m >= 1; m >>= 1) part += __shfl_xor(part, m);
    if ((tid & 15) == 0) score[row] = part;
  }
}

// ---------------- per-graph top-k via bitonic sort of (raw score desc, idx asc) ----------------
// ordering is invariant to the positive scale 1/||p||; apply it only inside tanh.

__global__ __launch_bounds__(1024) void topk_kernel(const float* __restrict__ score, const int* __restrict__ alive_cur,
      int* __restrict__ alive_next, float* __restrict__ tanhv, const float* __restrict__ p, int m){
  __shared__ float sv[1024];
  __shared__ int   si[1024];
  __shared__ float rnorm;
  int g = blockIdx.x, t = threadIdx.x;
  if (t < 64){
    float v0 = p[t], v1 = p[t + 64];
    float ss = v0*v0 + v1*v1;
    #pragma unroll
    for (int mm = 32; mm >= 1; mm >>= 1) ss += __shfl_xor(ss, mm);
    if (t == 0) rnorm = rsqrtf(ss);
  }
  int node = g*NPER + t;
  bool ok = alive_cur ? (alive_cur[node] != 0) : true;
  sv[t] = ok ? score[node] : -INFINITY;
  si[t] = node;
  alive_next[node] = 0;
  __syncthreads();
  for (int size = 2; size <= 1024; size <<= 1){
    for (int stride = size >> 1; stride > 0; stride >>= 1){
      int j = t ^ stride;
      if (j > t){
        float vt = sv[t], vj = sv[j];
        int   it = si[t], ij = si[j];
        bool beforeTJ = (vt > vj) || (vt == vj && it < ij);  // t belongs first
        bool ascending = ((t & size) == 0);
        bool dosw = ascending ? !beforeTJ : beforeTJ;
        if (dosw){ sv[t] = vj; sv[j] = vt; si[t] = ij; si[j] = it; }
      }
      __syncthreads();
    }
  }
  if (t < m){
    int idx = si[t];
    alive_next[idx] = 1;
    tanhv[idx] = tanhf(sv[t] * rnorm);
  }
}

// ---------------- fused: x = selected ? y*tanh(s) : 0  +  per-graph masked max/mean readout ----------------

__global__ __launch_bounds__(1024) void apply_readout_kernel(const float* __restrict__ y,
      const int* __restrict__ alive, const float* __restrict__ tanhv,
      float* __restrict__ x, float* __restrict__ h, int m){
  __shared__ float smx[32][33];
  __shared__ float ssm[32][33];
  int g = blockIdx.x;
  int fq = blockIdx.y;
  int t = threadIdx.x;
  int c  = t >> 5;         // node group 0..31
  int lf = t & 31;         // feature within quarter
  int f  = fq*32 + lf;
  int base = g*NPER;
  float mx = -INFINITY, sm = 0.f;
  #pragma unroll 4
  for (int i = 0; i < 32; ++i){
    int node = base + c + i*32;
    int al = alive[node];
    float tv = tanhv[node];           // garbage for dead nodes, never used
    float v = y[(size_t)node*128 + f];
    float o = al ? v*tv : 0.f;
    x[(size_t)node*128 + f] = o;
    mx = al ? fmaxf(mx, o) : mx;
    sm += o;
  }
  smx[c][lf] = mx; ssm[c][lf] = sm;
  __syncthreads();
  for (int s = 16; s > 0; s >>= 1){
    if (c < s){
      smx[c][lf] = fmaxf(smx[c][lf], smx[c+s][lf]);
      ssm[c][lf] += ssm[c+s][lf];
    }
    __syncthreads();
  }
  if (c == 0){
    h[g*256 + f]       += smx[0][lf];
    h[g*256 + 128 + f] += ssm[0][lf] / (float)m;
  }
}

// ---------------- final MLP + log_softmax ----------------

__global__ __launch_bounds__(128) void final_kernel(const float* __restrict__ h,
      const float* __restrict__ l1w, const float* __restrict__ l1b,
      const float* __restrict__ l2w, const float* __restrict__ l2b,
      float* __restrict__ out){
  int g = blockIdx.x, t = threadIdx.x;
  __shared__ float hrow[256];
  __shared__ float red0[128], red1[128];
  hrow[t]       = h[g*256 + t];
  hrow[t + 128] = h[g*256 + 128 + t];
  __syncthreads();
  float a = l1b[t];
  for (int k = 0; k < 256; ++k) a = fmaf(hrow[k], l1w[k*128 + t], a);
  a = fmaxf(a, 0.f);
  red0[t] = a * l2w[t*2 + 0];
  red1[t] = a * l2w[t*2 + 1];
  __syncthreads();
  for (int s = 64; s > 0; s >>= 1){
    if (t < s){ red0[t] += red0[t + s]; red1[t] += red1[t + s]; }
    __syncthreads();
  }
  if (t == 0){
    float z0 = fmaxf(red0[0] + l2b[0], 0.f);
    float z1 = fmaxf(red1[0] + l2b[1], 0.f);
    float mz = fmaxf(z0, z1);
    float lse = mz + logf(expf(z0 - mz) + expf(z1 - mz));
    out[g*2 + 0] = z0 - lse;
    out[g*2 + 1] = z1 - lse;
  }
}

// ---------------- host ----------------

static inline size_t alignup(size_t x){ return (x + 255) & ~(size_t)255; }

extern "C" void kernel_launch(void* const* d_in, const int* in_sizes, int n_in,
                              void* d_out, int out_size, void* d_ws, size_t ws_size,
                              hipStream_t stream) {
  const float* x_in = (const float*)d_in[0];
  const int*   ei   = (const int*)d_in[1];
  const float* Wr[3] = {(const float*)d_in[3], (const float*)d_in[6], (const float*)d_in[9]};
  const float* Wn[3] = {(const float*)d_in[4], (const float*)d_in[7], (const float*)d_in[10]};
  const float* bs[3] = {(const float*)d_in[5], (const float*)d_in[8], (const float*)d_in[11]};
  const float* ps[3] = {(const float*)d_in[12], (const float*)d_in[13], (const float*)d_in[14]};
  const float* l1w = (const float*)d_in[15];
  const float* l1b = (const float*)d_in[16];
  const float* l2w = (const float*)d_in[17];
  const float* l2b = (const float*)d_in[18];
  float* out = (float*)d_out;

  char* w = (char*)d_ws;
  size_t o = 0;
  auto take = [&](size_t bytes) -> void* { void* p = w + o; o = alignup(o + bytes); return p; };
  int*   off    = (int*)  take((size_t)(NN + 1) * 4);
  int*   adj    = (int*)  take((size_t)NE * 4);
  int*   cnt    = (int*)  take((size_t)NN * 4);
  int*   loc    = (int*)  take((size_t)NN * 4);
  int*   cursor = (int*)  take((size_t)NN * 4);
  int*   bsum   = (int*)  take(64 * 4);
  int*   boff   = (int*)  take(64 * 4);
  int*   aliveA = (int*)  take((size_t)NN * 4);
  int*   aliveB = (int*)  take((size_t)NN * 4);
  float* tanhv  = (float*)take((size_t)NN * 4);
  float* score  = (float*)take((size_t)NN * 4);
  float* h      = (float*)take((size_t)NB * 256 * 4);
  float* A      = (float*)take((size_t)NN * 128 * 4);  // node features (current level)
  float* Bb     = (float*)take((size_t)NN * 128 * 4);  // agg, then conv output y
  (void)ws_size; (void)n_in; (void)in_sizes; (void)out_size;

  // CSR build (by dst, storing src)
  hipMemsetAsync(cnt, 0, (size_t)NN * 4, stream);
  count_kernel<<<NE/256, 256, 0, stream>>>(ei, cnt);
  scan1_kernel<<<NN/1024, 1024, 0, stream>>>(cnt, loc, bsum);
  scan2_kernel<<<1, 64, 0, stream>>>(bsum, boff);
  scan3_kernel<<<NN/1024, 1024, 0, stream>>>(loc, boff, off, cursor);
  fill_kernel<<<NE/256, 256, 0, stream>>>(ei, cursor, adj);
  hipMemsetAsync(h, 0, (size_t)NB * 256 * 4, stream);

  const int MS[3] = {820, 656, 525};
  int* aliveCur = nullptr;
  int* aliveNext = aliveA;
  for (int l = 0; l < 3; ++l){
    if (l == 0){
      gather_kernel<<<NN*64/256, 256, 0, stream>>>(x_in, 64, 64, off, adj, Bb, nullptr);
      conv_kernel<<<NN/128, 512, 0, stream>>>(x_in, 64, 64, Wr[0], Bb, 64, Wn[0], bs[0], ps[0], Bb, score);
    } else {
      gather_kernel<<<NN*64/256, 256, 0, stream>>>(A, 128, 128, off, adj, Bb, aliveCur);
      conv_kernel<<<NN/128, 512, 0, stream>>>(A, 128, 128, Wr[l], Bb, 128, Wn[l], bs[l], ps[l], Bb, score);
    }
    topk_kernel<<<NB, 1024, 0, stream>>>(score, aliveCur, aliveNext, tanhv, ps[l], MS[l]);
    apply_readout_kernel<<<dim3(NB, 4), 1024, 0, stream>>>(Bb, aliveNext, tanhv, A, h, MS[l]);
    aliveCur = aliveNext;
    aliveNext = (l == 0) ? aliveB : aliveA;
  }
  final_kernel<<<NB, 128, 0, stream>>>(h, l1w, l1b, l2w, l2b, out);
}

// Round 9
// 363.165 us; speedup vs baseline: 1.4489x; 1.2510x over previous
//
#include <hip/hip_runtime.h>
#include <hip/hip_bf16.h>
#include <math.h>

#define NN   65536      // total nodes
#define NPER 1024       // nodes per graph
#define NE   1048576    // edges
#define NB   64         // graphs

typedef __attribute__((ext_vector_type(8))) short short8;   // 8 bf16 = 4 VGPR
typedef __attribute__((ext_vector_type(4))) float f32x4;    // MFMA acc

// ---------------- CSR build ----------------

__global__ __launch_bounds__(256) void count_kernel(const int* __restrict__ ei, int* __restrict__ cnt){
  int e = blockIdx.x*256 + threadIdx.x;
  if (e < NE) atomicAdd(&cnt[ei[NE + e]], 1);
}

__global__ __launch_bounds__(1024) void scan1_kernel(const int* __restrict__ cnt,
      int* __restrict__ loc, int* __restrict__ bsum){
  __shared__ int wsum[16];
  int t = threadIdx.x;
  int i = blockIdx.x*1024 + t;
  int lane = t & 63, wid = t >> 6;
  int v = cnt[i];
  int s = v;
  #pragma unroll
  for (int d = 1; d < 64; d <<= 1){
    int src = (lane >= d) ? (lane - d) : lane;
    int u = __shfl(s, src);
    if (lane >= d) s += u;
  }
  if (lane == 63) wsum[wid] = s;
  __syncthreads();
  if (wid == 0){
    int ws = (lane < 16) ? wsum[lane] : 0;
    #pragma unroll
    for (int d = 1; d < 16; d <<= 1){
      int src = (lane >= d) ? (lane - d) : lane;
      int u = __shfl(ws, src);
      if (lane >= d) ws += u;
    }
    if (lane < 16) wsum[lane] = ws;
  }
  __syncthreads();
  int base = (wid > 0) ? wsum[wid - 1] : 0;
  loc[i] = base + s - v;                 // exclusive within block
  if (t == 1023) bsum[blockIdx.x] = base + s;
}

__global__ __launch_bounds__(64) void scan2_kernel(const int* __restrict__ bsum, int* __restrict__ boff){
  int t = threadIdx.x;
  int v = bsum[t];
  int s = v;
  #pragma unroll
  for (int d = 1; d < 64; d <<= 1){
    int src = (t >= d) ? (t - d) : t;
    int u = __shfl(s, src);
    if (t >= d) s += u;
  }
  boff[t] = s - v;
}

__global__ __launch_bounds__(1024) void scan3_kernel(const int* __restrict__ loc, const int* __restrict__ boff,
      int* __restrict__ off, int* __restrict__ cursor){
  int i = blockIdx.x*1024 + threadIdx.x;
  int v = loc[i] + boff[blockIdx.x];
  off[i] = v;
  cursor[i] = v;
  if (i == NN - 1) off[NN] = NE;
}

__global__ __launch_bounds__(256) void fill_kernel(const int* __restrict__ ei, int* cursor, int* __restrict__ adj){
  int e = blockIdx.x*256 + threadIdx.x;
  if (e < NE){
    int pos = atomicAdd(&cursor[ei[NE + e]], 1);
    adj[pos] = ei[e];
  }
}

// ---------------- aggregation (segment_sum of x[src] into dst rows) ----------------
// one wave per node, float4 per lane, 8 row-loads in flight, XCD-chunked swizzle.

__global__ __launch_bounds__(256) void gather_kernel(const float* __restrict__ x, int stride, int F,
      const int* __restrict__ off, const int* __restrict__ adj, float* __restrict__ agg,
      const int* __restrict__ alive){
  int bid = blockIdx.x;
  bid = (bid & 7) * (gridDim.x >> 3) + (bid >> 3);   // round-robin XCD -> contiguous chunks
  int w = (bid*256 + (int)threadIdx.x) >> 6;
  int lane = threadIdx.x & 63;
  if (w >= NN) return;
  if (alive && !alive[w]) return;
  int s0 = off[w], s1 = off[w+1];
  if (F == 64){
    int sub = lane >> 4;            // edge-group 0..3
    int fl  = (lane & 15) * 4;      // features fl..fl+3
    float4 a0 = {0,0,0,0}, a1 = {0,0,0,0};
    for (int e = s0; e < s1; e += 8){
      int e0 = e + sub, e1 = e + 4 + sub;
      if (e0 < s1){
        float4 v = *(const float4*)&x[(size_t)adj[e0]*stride + fl];
        a0.x += v.x; a0.y += v.y; a0.z += v.z; a0.w += v.w;
      }
      if (e1 < s1){
        float4 v = *(const float4*)&x[(size_t)adj[e1]*stride + fl];
        a1.x += v.x; a1.y += v.y; a1.z += v.z; a1.w += v.w;
      }
    }
    a0.x += a1.x; a0.y += a1.y; a0.z += a1.z; a0.w += a1.w;
    #pragma unroll
    for (int m = 16; m <= 32; m <<= 1){
      a0.x += __shfl_xor(a0.x, m);
      a0.y += __shfl_xor(a0.y, m);
      a0.z += __shfl_xor(a0.z, m);
      a0.w += __shfl_xor(a0.w, m);
    }
    if (lane < 16) *(float4*)&agg[(size_t)w*128 + fl] = a0;
  } else {
    int sub = lane >> 5;            // edge-group 0..1
    int fl  = (lane & 31) * 4;
    float4 a0 = {0,0,0,0}, a1 = {0,0,0,0}, a2 = {0,0,0,0}, a3 = {0,0,0,0};
    for (int e = s0; e < s1; e += 8){
      int e0 = e + sub, e1 = e + 2 + sub, e2 = e + 4 + sub, e3 = e + 6 + sub;
      if (e0 < s1){
        float4 v = *(const float4*)&x[(size_t)adj[e0]*stride + fl];
        a0.x += v.x; a0.y += v.y; a0.z += v.z; a0.w += v.w;
      }
      if (e1 < s1){
        float4 v = *(const float4*)&x[(size_t)adj[e1]*stride + fl];
        a1.x += v.x; a1.y += v.y; a1.z += v.z; a1.w += v.w;
      }
      if (e2 < s1){
        float4 v = *(const float4*)&x[(size_t)adj[e2]*stride + fl];
        a2.x += v.x; a2.y += v.y; a2.z += v.z; a2.w += v.w;
      }
      if (e3 < s1){
        float4 v = *(const float4*)&x[(size_t)adj[e3]*stride + fl];
        a3.x += v.x; a3.y += v.y; a3.z += v.z; a3.w += v.w;
      }
    }
    a0.x += a1.x + a2.x + a3.x;
    a0.y += a1.y + a2.y + a3.y;
    a0.z += a1.z + a2.z + a3.z;
    a0.w += a1.w + a2.w + a3.w;
    a0.x += __shfl_xor(a0.x, 32);
    a0.y += __shfl_xor(a0.y, 32);
    a0.z += __shfl_xor(a0.z, 32);
    a0.w += __shfl_xor(a0.w, 32);
    if (lane < 32) *(float4*)&agg[(size_t)w*128 + fl] = a0;
  }
}

// ---------------- W prep: Wcat = [Wr;Wn] -> transposed bf16 hi/lo WT[col][k] ----------------

__global__ __launch_bounds__(256) void wsplit_kernel(const float* __restrict__ Wr, const float* __restrict__ Wn,
      int Kx, int Kcat, unsigned short* __restrict__ WTh, unsigned short* __restrict__ WTl){
  int idx = blockIdx.x*256 + threadIdx.x;
  if (idx >= Kcat*128) return;
  int c = idx & 127, k = idx >> 7;
  float w = (k < Kx) ? Wr[k*128 + c] : Wn[(k - Kx)*128 + c];
  __hip_bfloat16 h = __float2bfloat16(w);
  float hf = __bfloat162float(h);
  __hip_bfloat16 l = __float2bfloat16(w - hf);
  WTh[(size_t)c*Kcat + k] = reinterpret_cast<unsigned short&>(h);
  WTl[(size_t)c*Kcat + k] = reinterpret_cast<unsigned short&>(l);
}

// ---------------- conv via bf16x3 MFMA: y = relu(x@Wr + agg@Wn + b), score = y.p ----------------
// 128x128 tile, 256 threads = 2x2 waves of 64x64. mfma_f32_16x16x32_bf16:
// A frag: row=lane&15, k=(lane>>4)*8+j ; B frag: col=lane&15, same k ;
// C frag: col=lane&15, row=(lane>>4)*4+reg (verified layout).
// Split product: Xh*Wh + Xh*Wl + Xl*Wh (fp32-comparable, keeps topk ordering).
// LDS: X/W tiles as bf16 hi/lo, 16B k-quad slots XOR-swizzled by (row&3)/(col&3).
// NOTE: yout aliases aggb: staging reads of a block's own rows all complete
// before the last barrier; epilogue writes after.

__global__ __launch_bounds__(256, 2) void conv_kernel(const float* __restrict__ xsrc, int strideX, int ntx,
      const float* aggb, int nta,
      const unsigned short* __restrict__ WTh, const unsigned short* __restrict__ WTl, int Kcat,
      const float* __restrict__ bias, const float* __restrict__ p,
      float* yout, float* __restrict__ score){
  __shared__ unsigned short XhL[128*32], XlL[128*32];
  __shared__ unsigned short WhL[128*32], WlL[128*32];
  __shared__ float sbuf[128*2];
  const int tid = threadIdx.x;
  const int row0 = blockIdx.x * 128;
  const int srow = tid & 127;          // staging row (X) / col (W)
  const int shalf = tid >> 7;          // staging k-half (16 k each)
  const int lane = tid & 63;
  const int wid = tid >> 6;            // 4 waves: 2x2
  const int wr = wid >> 1, wc = wid & 1;
  const int l15 = lane & 15, lkq = lane >> 4;

  f32x4 acc[4][4];
  #pragma unroll
  for (int m = 0; m < 4; ++m)
    #pragma unroll
    for (int j = 0; j < 4; ++j)
      acc[m][j] = (f32x4){0.f, 0.f, 0.f, 0.f};

  const int nt = ntx + nta;
  for (int t = 0; t < nt; ++t){
    __syncthreads();                   // previous tile's compute done
    // ---- stage X (fp32 -> bf16 hi/lo) ----
    {
      const float* Xs   = (t < ntx) ? xsrc : aggb;
      const int stride  = (t < ntx) ? strideX : 128;
      const int kc      = (t < ntx) ? t*32 : (t - ntx)*32;
      #pragma unroll
      for (int kq2 = 0; kq2 < 2; ++kq2){
        const int kq = shalf*2 + kq2;
        const float* xp = Xs + (size_t)(row0 + srow)*stride + kc + kq*8;
        float4 v0 = *(const float4*)(xp);
        float4 v1 = *(const float4*)(xp + 4);
        float vv[8] = {v0.x, v0.y, v0.z, v0.w, v1.x, v1.y, v1.z, v1.w};
        short8 hs, ls;
        #pragma unroll
        for (int q = 0; q < 8; ++q){
          __hip_bfloat16 h = __float2bfloat16(vv[q]);
          float hf = __bfloat162float(h);
          __hip_bfloat16 lo = __float2bfloat16(vv[q] - hf);
          hs[q] = reinterpret_cast<short&>(h);
          ls[q] = reinterpret_cast<short&>(lo);
        }
        const int kqph = kq ^ (srow & 3);
        *(short8*)&XhL[srow*32 + kqph*8] = hs;
        *(short8*)&XlL[srow*32 + kqph*8] = ls;
      }
      // ---- stage W (already bf16 hi/lo, [col][k]) ----
      const int kcw = t*32;
      #pragma unroll
      for (int kq2 = 0; kq2 < 2; ++kq2){
        const int kq = shalf*2 + kq2;
        short8 h = *(const short8*)&WTh[(size_t)srow*Kcat + kcw + kq*8];
        short8 l = *(const short8*)&WTl[(size_t)srow*Kcat + kcw + kq*8];
        const int kqph = kq ^ (srow & 3);
        *(short8*)&WhL[srow*32 + kqph*8] = h;
        *(short8*)&WlL[srow*32 + kqph*8] = l;
      }
    }
    __syncthreads();
    // ---- MFMA: wave (wr,wc) computes rows wr*64..+63 x cols wc*64..+63 ----
    short8 bh[4], bl[4];
    #pragma unroll
    for (int j = 0; j < 4; ++j){
      const int col = wc*64 + j*16 + l15;
      const int offb = col*32 + (lkq ^ (col & 3))*8;
      bh[j] = *(const short8*)&WhL[offb];
      bl[j] = *(const short8*)&WlL[offb];
    }
    #pragma unroll
    for (int m = 0; m < 4; ++m){
      const int row = wr*64 + m*16 + l15;
      const int offa = row*32 + (lkq ^ (row & 3))*8;
      short8 ah = *(const short8*)&XhL[offa];
      short8 al = *(const short8*)&XlL[offa];
      #pragma unroll
      for (int j = 0; j < 4; ++j){
        acc[m][j] = __builtin_amdgcn_mfma_f32_16x16x32_bf16(ah, bh[j], acc[m][j], 0, 0, 0);
        acc[m][j] = __builtin_amdgcn_mfma_f32_16x16x32_bf16(ah, bl[j], acc[m][j], 0, 0, 0);
        acc[m][j] = __builtin_amdgcn_mfma_f32_16x16x32_bf16(al, bh[j], acc[m][j], 0, 0, 0);
      }
    }
  }

  // ---- epilogue: relu + bias, store y, fused score partials ----
  #pragma unroll
  for (int m = 0; m < 4; ++m){
    float prt[4] = {0.f, 0.f, 0.f, 0.f};
    #pragma unroll
    for (int j = 0; j < 4; ++j){
      const int col = wc*64 + j*16 + l15;
      const float bcol = bias[col];
      const float pcol = p[col];
      f32x4 a = acc[m][j];
      #pragma unroll
      for (int r = 0; r < 4; ++r){
        const int row = wr*64 + m*16 + lkq*4 + r;
        float y = fmaxf(a[r] + bcol, 0.f);
        yout[(size_t)(row0 + row)*128 + col] = y;
        prt[r] = fmaf(y, pcol, prt[r]);
      }
    }
    #pragma unroll
    for (int r = 0; r < 4; ++r){
      #pragma unroll
      for (int msk = 8; msk >= 1; msk >>= 1) prt[r] += __shfl_xor(prt[r], msk);
      if (l15 == 0) sbuf[(wr*64 + m*16 + lkq*4 + r)*2 + wc] = prt[r];
    }
  }
  __syncthreads();
  if (tid < 128) score[row0 + tid] = sbuf[tid*2] + sbuf[tid*2 + 1];
}

// ---------------- per-graph top-k via bitonic sort of (raw score desc, idx asc) ----------------

__global__ __launch_bounds__(1024) void topk_kernel(const float* __restrict__ score, const int* __restrict__ alive_cur,
      int* __restrict__ alive_next, float* __restrict__ tanhv, const float* __restrict__ p, int m){
  __shared__ float sv[1024];
  __shared__ int   si[1024];
  __shared__ float rnorm;
  int g = blockIdx.x, t = threadIdx.x;
  if (t < 64){
    float v0 = p[t], v1 = p[t + 64];
    float ss = v0*v0 + v1*v1;
    #pragma unroll
    for (int mm = 32; mm >= 1; mm >>= 1) ss += __shfl_xor(ss, mm);
    if (t == 0) rnorm = rsqrtf(ss);
  }
  int node = g*NPER + t;
  bool ok = alive_cur ? (alive_cur[node] != 0) : true;
  sv[t] = ok ? score[node] : -INFINITY;
  si[t] = node;
  alive_next[node] = 0;
  __syncthreads();
  for (int size = 2; size <= 1024; size <<= 1){
    for (int stride = size >> 1; stride > 0; stride >>= 1){
      int j = t ^ stride;
      if (j > t){
        float vt = sv[t], vj = sv[j];
        int   it = si[t], ij = si[j];
        bool beforeTJ = (vt > vj) || (vt == vj && it < ij);  // t belongs first
        bool ascending = ((t & size) == 0);
        bool dosw = ascending ? !beforeTJ : beforeTJ;
        if (dosw){ sv[t] = vj; sv[j] = vt; si[t] = ij; si[j] = it; }
      }
      __syncthreads();
    }
  }
  if (t < m){
    int idx = si[t];
    alive_next[idx] = 1;
    tanhv[idx] = tanhf(sv[t] * rnorm);
  }
}

// ---------------- fused: x = selected ? y*tanh(s) : 0  +  per-graph masked max/mean readout ----------------

__global__ __launch_bounds__(1024) void apply_readout_kernel(const float* __restrict__ y,
      const int* __restrict__ alive, const float* __restrict__ tanhv,
      float* __restrict__ x, float* __restrict__ h, int m){
  __shared__ float smx[32][33];
  __shared__ float ssm[32][33];
  int g = blockIdx.x;
  int fq = blockIdx.y;
  int t = threadIdx.x;
  int c  = t >> 5;         // node group 0..31
  int lf = t & 31;         // feature within quarter
  int f  = fq*32 + lf;
  int base = g*NPER;
  float mx = -INFINITY, sm = 0.f;
  #pragma unroll 4
  for (int i = 0; i < 32; ++i){
    int node = base + c + i*32;
    int al = alive[node];
    float tv = tanhv[node];           // garbage for dead nodes, never used
    float v = y[(size_t)node*128 + f];
    float o = al ? v*tv : 0.f;
    x[(size_t)node*128 + f] = o;
    mx = al ? fmaxf(mx, o) : mx;
    sm += o;
  }
  smx[c][lf] = mx; ssm[c][lf] = sm;
  __syncthreads();
  for (int s = 16; s > 0; s >>= 1){
    if (c < s){
      smx[c][lf] = fmaxf(smx[c][lf], smx[c+s][lf]);
      ssm[c][lf] += ssm[c+s][lf];
    }
    __syncthreads();
  }
  if (c == 0){
    h[g*256 + f]       += smx[0][lf];
    h[g*256 + 128 + f] += ssm[0][lf] / (float)m;
  }
}

// ---------------- final MLP + log_softmax ----------------

__global__ __launch_bounds__(128) void final_kernel(const float* __restrict__ h,
      const float* __restrict__ l1w, const float* __restrict__ l1b,
      const float* __restrict__ l2w, const float* __restrict__ l2b,
      float* __restrict__ out){
  int g = blockIdx.x, t = threadIdx.x;
  __shared__ float hrow[256];
  __shared__ float red0[128], red1[128];
  hrow[t]       = h[g*256 + t];
  hrow[t + 128] = h[g*256 + 128 + t];
  __syncthreads();
  float a = l1b[t];
  for (int k = 0; k < 256; ++k) a = fmaf(hrow[k], l1w[k*128 + t], a);
  a = fmaxf(a, 0.f);
  red0[t] = a * l2w[t*2 + 0];
  red1[t] = a * l2w[t*2 + 1];
  __syncthreads();
  for (int s = 64; s > 0; s >>= 1){
    if (t < s){ red0[t] += red0[t + s]; red1[t] += red1[t + s]; }
    __syncthreads();
  }
  if (t == 0){
    float z0 = fmaxf(red0[0] + l2b[0], 0.f);
    float z1 = fmaxf(red1[0] + l2b[1], 0.f);
    float mz = fmaxf(z0, z1);
    float lse = mz + logf(expf(z0 - mz) + expf(z1 - mz));
    out[g*2 + 0] = z0 - lse;
    out[g*2 + 1] = z1 - lse;
  }
}

// ---------------- host ----------------

static inline size_t alignup(size_t x){ return (x + 255) & ~(size_t)255; }

extern "C" void kernel_launch(void* const* d_in, const int* in_sizes, int n_in,
                              void* d_out, int out_size, void* d_ws, size_t ws_size,
                              hipStream_t stream) {
  const float* x_in = (const float*)d_in[0];
  const int*   ei   = (const int*)d_in[1];
  const float* Wr[3] = {(const float*)d_in[3], (const float*)d_in[6], (const float*)d_in[9]};
  const float* Wn[3] = {(const float*)d_in[4], (const float*)d_in[7], (const float*)d_in[10]};
  const float* bs[3] = {(const float*)d_in[5], (const float*)d_in[8], (const float*)d_in[11]};
  const float* ps[3] = {(const float*)d_in[12], (const float*)d_in[13], (const float*)d_in[14]};
  const float* l1w = (const float*)d_in[15];
  const float* l1b = (const float*)d_in[16];
  const float* l2w = (const float*)d_in[17];
  const float* l2b = (const float*)d_in[18];
  float* out = (float*)d_out;

  char* w = (char*)d_ws;
  size_t o = 0;
  auto take = [&](size_t bytes) -> void* { void* p = w + o; o = alignup(o + bytes); return p; };
  int*   off    = (int*)  take((size_t)(NN + 1) * 4);
  int*   adj    = (int*)  take((size_t)NE * 4);
  int*   cnt    = (int*)  take((size_t)NN * 4);
  int*   loc    = (int*)  take((size_t)NN * 4);
  int*   cursor = (int*)  take((size_t)NN * 4);
  int*   bsum   = (int*)  take(64 * 4);
  int*   boff   = (int*)  take(64 * 4);
  int*   aliveA = (int*)  take((size_t)NN * 4);
  int*   aliveB = (int*)  take((size_t)NN * 4);
  float* tanhv  = (float*)take((size_t)NN * 4);
  float* score  = (float*)take((size_t)NN * 4);
  float* h      = (float*)take((size_t)NB * 256 * 4);
  unsigned short* WTh = (unsigned short*)take((size_t)128 * 256 * 2);
  unsigned short* WTl = (unsigned short*)take((size_t)128 * 256 * 2);
  float* A      = (float*)take((size_t)NN * 128 * 4);  // node features (current level)
  float* Bb     = (float*)take((size_t)NN * 128 * 4);  // agg, then conv output y
  (void)ws_size; (void)n_in; (void)in_sizes; (void)out_size;

  // CSR build (by dst, storing src)
  hipMemsetAsync(cnt, 0, (size_t)NN * 4, stream);
  count_kernel<<<NE/256, 256, 0, stream>>>(ei, cnt);
  scan1_kernel<<<NN/1024, 1024, 0, stream>>>(cnt, loc, bsum);
  scan2_kernel<<<1, 64, 0, stream>>>(bsum, boff);
  scan3_kernel<<<NN/1024, 1024, 0, stream>>>(loc, boff, off, cursor);
  fill_kernel<<<NE/256, 256, 0, stream>>>(ei, cursor, adj);
  hipMemsetAsync(h, 0, (size_t)NB * 256 * 4, stream);

  const int MS[3] = {820, 656, 525};
  int* aliveCur = nullptr;
  int* aliveNext = aliveA;
  for (int l = 0; l < 3; ++l){
    const int Kx = (l == 0) ? 64 : 128;
    const int Ka = (l == 0) ? 64 : 128;
    const int Kcat = Kx + Ka;
    wsplit_kernel<<<(Kcat*128 + 255)/256, 256, 0, stream>>>(Wr[l], Wn[l], Kx, Kcat, WTh, WTl);
    if (l == 0){
      gather_kernel<<<NN*64/256, 256, 0, stream>>>(x_in, 64, 64, off, adj, Bb, nullptr);
      conv_kernel<<<NN/128, 256, 0, stream>>>(x_in, 64, Kx/32, Bb, Ka/32, WTh, WTl, Kcat, bs[0], ps[0], Bb, score);
    } else {
      gather_kernel<<<NN*64/256, 256, 0, stream>>>(A, 128, 128, off, adj, Bb, aliveCur);
      conv_kernel<<<NN/128, 256, 0, stream>>>(A, 128, Kx/32, Bb, Ka/32, WTh, WTl, Kcat, bs[l], ps[l], Bb, score);
    }
    topk_kernel<<<NB, 1024, 0, stream>>>(score, aliveCur, aliveNext, tanhv, ps[l], MS[l]);
    apply_readout_kernel<<<dim3(NB, 4), 1024, 0, stream>>>(Bb, aliveNext, tanhv, A, h, MS[l]);
    aliveCur = aliveNext;
    aliveNext = (l == 0) ? aliveB : aliveA;
  }
  final_kernel<<<NB, 128, 0, stream>>>(h, l1w, l1b, l2w, l2b, out);
}

// Round 10
// 362.704 us; speedup vs baseline: 1.4508x; 1.0013x over previous
//
#include <hip/hip_runtime.h>
#include <hip/hip_bf16.h>
#include <math.h>

#define NN   65536      // total nodes
#define NPER 1024       // nodes per graph
#define NE   1048576    // edges
#define NB   64         // graphs

typedef __attribute__((ext_vector_type(8))) short short8;   // 8 bf16 = 4 VGPR
typedef __attribute__((ext_vector_type(4))) float f32x4;    // MFMA acc

// ---------------- CSR build ----------------

__global__ __launch_bounds__(256) void count_kernel(const int* __restrict__ ei, int* __restrict__ cnt){
  int e = blockIdx.x*256 + threadIdx.x;
  if (e < NE) atomicAdd(&cnt[ei[NE + e]], 1);
}

__global__ __launch_bounds__(1024) void scan1_kernel(const int* __restrict__ cnt,
      int* __restrict__ loc, int* __restrict__ bsum){
  __shared__ int wsum[16];
  int t = threadIdx.x;
  int i = blockIdx.x*1024 + t;
  int lane = t & 63, wid = t >> 6;
  int v = cnt[i];
  int s = v;
  #pragma unroll
  for (int d = 1; d < 64; d <<= 1){
    int src = (lane >= d) ? (lane - d) : lane;
    int u = __shfl(s, src);
    if (lane >= d) s += u;
  }
  if (lane == 63) wsum[wid] = s;
  __syncthreads();
  if (wid == 0){
    int ws = (lane < 16) ? wsum[lane] : 0;
    #pragma unroll
    for (int d = 1; d < 16; d <<= 1){
      int src = (lane >= d) ? (lane - d) : lane;
      int u = __shfl(ws, src);
      if (lane >= d) ws += u;
    }
    if (lane < 16) wsum[lane] = ws;
  }
  __syncthreads();
  int base = (wid > 0) ? wsum[wid - 1] : 0;
  loc[i] = base + s - v;                 // exclusive within block
  if (t == 1023) bsum[blockIdx.x] = base + s;
}

__global__ __launch_bounds__(64) void scan2_kernel(const int* __restrict__ bsum, int* __restrict__ boff){
  int t = threadIdx.x;
  int v = bsum[t];
  int s = v;
  #pragma unroll
  for (int d = 1; d < 64; d <<= 1){
    int src = (t >= d) ? (t - d) : t;
    int u = __shfl(s, src);
    if (t >= d) s += u;
  }
  boff[t] = s - v;
}

__global__ __launch_bounds__(1024) void scan3_kernel(const int* __restrict__ loc, const int* __restrict__ boff,
      int* __restrict__ off, int* __restrict__ cursor){
  int i = blockIdx.x*1024 + threadIdx.x;
  int v = loc[i] + boff[blockIdx.x];
  off[i] = v;
  cursor[i] = v;
  if (i == NN - 1) off[NN] = NE;
}

__global__ __launch_bounds__(256) void fill_kernel(const int* __restrict__ ei, int* cursor, int* __restrict__ adj){
  int e = blockIdx.x*256 + threadIdx.x;
  if (e < NE){
    int pos = atomicAdd(&cursor[ei[NE + e]], 1);
    adj[pos] = ei[e];
  }
}

// ---------------- aggregation: agg[w] = sum_e scale[src_e] * y[src_e] ----------------
// one wave per dst node, float4 per lane, XCD-chunked swizzle.
// F==64 (level 0): scale==null, plain sum, 4 lane-groups x 4 deep (16 edges/iter).
// F==128: 2 lane-groups x 8 deep (16 edges/iter, 8 row-loads in flight);
// rows with scale==0 are SKIPPED (contribution exactly zero -> no read).

__global__ __launch_bounds__(256) void gather_kernel(const float* __restrict__ x, int stride, int F,
      const int* __restrict__ off, const int* __restrict__ adj, float* __restrict__ agg,
      const int* __restrict__ alive, const float* __restrict__ scale){
  int bid = blockIdx.x;
  bid = (bid & 7) * (gridDim.x >> 3) + (bid >> 3);   // round-robin XCD -> contiguous chunks
  int w = (bid*256 + (int)threadIdx.x) >> 6;
  int lane = threadIdx.x & 63;
  if (w >= NN) return;
  if (alive && !alive[w]) return;
  int s0 = off[w], s1 = off[w+1];
  if (F == 64){
    int sub = lane >> 4;            // edge-group 0..3
    int fl  = (lane & 15) * 4;      // features fl..fl+3
    float4 a[4];
    #pragma unroll
    for (int i = 0; i < 4; ++i) a[i] = make_float4(0.f,0.f,0.f,0.f);
    for (int e = s0; e < s1; e += 16){
      #pragma unroll
      for (int i = 0; i < 4; ++i){
        int ei = e + 4*i + sub;
        if (ei < s1){
          float4 v = *(const float4*)&x[(size_t)adj[ei]*stride + fl];
          a[i].x += v.x; a[i].y += v.y; a[i].z += v.z; a[i].w += v.w;
        }
      }
    }
    float4 r;
    r.x = a[0].x + a[1].x + a[2].x + a[3].x;
    r.y = a[0].y + a[1].y + a[2].y + a[3].y;
    r.z = a[0].z + a[1].z + a[2].z + a[3].z;
    r.w = a[0].w + a[1].w + a[2].w + a[3].w;
    #pragma unroll
    for (int m = 16; m <= 32; m <<= 1){
      r.x += __shfl_xor(r.x, m);
      r.y += __shfl_xor(r.y, m);
      r.z += __shfl_xor(r.z, m);
      r.w += __shfl_xor(r.w, m);
    }
    if (lane < 16) *(float4*)&agg[(size_t)w*128 + fl] = r;
  } else {
    int sub = lane >> 5;            // edge-group 0..1
    int fl  = (lane & 31) * 4;
    float4 a[8];
    #pragma unroll
    for (int i = 0; i < 8; ++i) a[i] = make_float4(0.f,0.f,0.f,0.f);
    for (int e = s0; e < s1; e += 16){
      int ss[8]; float tv[8];
      #pragma unroll
      for (int i = 0; i < 8; ++i){
        int ei = e + 2*i + sub;
        int s = (ei < s1) ? adj[ei] : 0;
        ss[i] = s;
        float t = scale[s];
        tv[i] = (ei < s1) ? t : 0.f;
      }
      #pragma unroll
      for (int i = 0; i < 8; ++i){
        if (tv[i] != 0.f){
          float4 v = *(const float4*)&x[(size_t)ss[i]*stride + fl];
          a[i].x += v.x*tv[i]; a[i].y += v.y*tv[i]; a[i].z += v.z*tv[i]; a[i].w += v.w*tv[i];
        }
      }
    }
    float4 r;
    r.x = (a[0].x+a[1].x)+(a[2].x+a[3].x)+((a[4].x+a[5].x)+(a[6].x+a[7].x));
    r.y = (a[0].y+a[1].y)+(a[2].y+a[3].y)+((a[4].y+a[5].y)+(a[6].y+a[7].y));
    r.z = (a[0].z+a[1].z)+(a[2].z+a[3].z)+((a[4].z+a[5].z)+(a[6].z+a[7].z));
    r.w = (a[0].w+a[1].w)+(a[2].w+a[3].w)+((a[4].w+a[5].w)+(a[6].w+a[7].w));
    r.x += __shfl_xor(r.x, 32);
    r.y += __shfl_xor(r.y, 32);
    r.z += __shfl_xor(r.z, 32);
    r.w += __shfl_xor(r.w, 32);
    if (lane < 32) *(float4*)&agg[(size_t)w*128 + fl] = r;
  }
}

// ---------------- W prep: Wcat = [Wr;Wn] -> transposed bf16 hi/lo WT[col][k] ----------------

__global__ __launch_bounds__(256) void wsplit_kernel(const float* __restrict__ Wr, const float* __restrict__ Wn,
      int Kx, int Kcat, unsigned short* __restrict__ WTh, unsigned short* __restrict__ WTl){
  int idx = blockIdx.x*256 + threadIdx.x;
  if (idx >= Kcat*128) return;
  int c = idx & 127, k = idx >> 7;
  float w = (k < Kx) ? Wr[k*128 + c] : Wn[(k - Kx)*128 + c];
  __hip_bfloat16 h = __float2bfloat16(w);
  float hf = __bfloat162float(h);
  __hip_bfloat16 l = __float2bfloat16(w - hf);
  WTh[(size_t)c*Kcat + k] = reinterpret_cast<unsigned short&>(h);
  WTl[(size_t)c*Kcat + k] = reinterpret_cast<unsigned short&>(l);
}

// ---------------- conv via bf16x3 MFMA: y = relu((scale.x)@Wr + agg@Wn + b), score = y.p ----
// 128x128 tile, 256 threads = 2x2 waves of 64x64, mfma_f32_16x16x32_bf16, split product
// Xh*Wh + Xh*Wl + Xl*Wh. X rows scaled by scaleX[row] (tanh-fold) during self-term staging.
// NOTE: yout aliases aggb: staging reads of a block's own rows all complete
// before the last barrier; epilogue writes after.

__global__ __launch_bounds__(256, 2) void conv_kernel(const float* __restrict__ xsrc, int strideX, int ntx,
      const float* aggb, int nta,
      const unsigned short* __restrict__ WTh, const unsigned short* __restrict__ WTl, int Kcat,
      const float* __restrict__ bias, const float* __restrict__ p, const float* __restrict__ scaleX,
      float* yout, float* __restrict__ score){
  __shared__ unsigned short XhL[128*32], XlL[128*32];
  __shared__ unsigned short WhL[128*32], WlL[128*32];
  __shared__ float sbuf[128*2];
  const int tid = threadIdx.x;
  const int row0 = blockIdx.x * 128;
  const int srow = tid & 127;          // staging row (X) / col (W)
  const int shalf = tid >> 7;          // staging k-half (16 k each)
  const int lane = tid & 63;
  const int wid = tid >> 6;            // 4 waves: 2x2
  const int wr = wid >> 1, wc = wid & 1;
  const int l15 = lane & 15, lkq = lane >> 4;

  const float xscale = scaleX ? scaleX[row0 + srow] : 1.f;

  f32x4 acc[4][4];
  #pragma unroll
  for (int m = 0; m < 4; ++m)
    #pragma unroll
    for (int j = 0; j < 4; ++j)
      acc[m][j] = (f32x4){0.f, 0.f, 0.f, 0.f};

  const int nt = ntx + nta;
  for (int t = 0; t < nt; ++t){
    __syncthreads();                   // previous tile's compute done
    // ---- stage X (fp32 -> scale -> bf16 hi/lo) ----
    {
      const float* Xs   = (t < ntx) ? xsrc : aggb;
      const int stride  = (t < ntx) ? strideX : 128;
      const int kc      = (t < ntx) ? t*32 : (t - ntx)*32;
      const float sc    = (t < ntx) ? xscale : 1.f;
      #pragma unroll
      for (int kq2 = 0; kq2 < 2; ++kq2){
        const int kq = shalf*2 + kq2;
        const float* xp = Xs + (size_t)(row0 + srow)*stride + kc + kq*8;
        float4 v0 = *(const float4*)(xp);
        float4 v1 = *(const float4*)(xp + 4);
        float vv[8] = {v0.x*sc, v0.y*sc, v0.z*sc, v0.w*sc,
                       v1.x*sc, v1.y*sc, v1.z*sc, v1.w*sc};
        short8 hs, ls;
        #pragma unroll
        for (int q = 0; q < 8; ++q){
          __hip_bfloat16 h = __float2bfloat16(vv[q]);
          float hf = __bfloat162float(h);
          __hip_bfloat16 lo = __float2bfloat16(vv[q] - hf);
          hs[q] = reinterpret_cast<short&>(h);
          ls[q] = reinterpret_cast<short&>(lo);
        }
        const int kqph = kq ^ (srow & 3);
        *(short8*)&XhL[srow*32 + kqph*8] = hs;
        *(short8*)&XlL[srow*32 + kqph*8] = ls;
      }
      // ---- stage W (already bf16 hi/lo, [col][k]) ----
      const int kcw = t*32;
      #pragma unroll
      for (int kq2 = 0; kq2 < 2; ++kq2){
        const int kq = shalf*2 + kq2;
        short8 h = *(const short8*)&WTh[(size_t)srow*Kcat + kcw + kq*8];
        short8 l = *(const short8*)&WTl[(size_t)srow*Kcat + kcw + kq*8];
        const int kqph = kq ^ (srow & 3);
        *(short8*)&WhL[srow*32 + kqph*8] = h;
        *(short8*)&WlL[srow*32 + kqph*8] = l;
      }
    }
    __syncthreads();
    // ---- MFMA: wave (wr,wc) computes rows wr*64..+63 x cols wc*64..+63 ----
    short8 bh[4], bl[4];
    #pragma unroll
    for (int j = 0; j < 4; ++j){
      const int col = wc*64 + j*16 + l15;
      const int offb = col*32 + (lkq ^ (col & 3))*8;
      bh[j] = *(const short8*)&WhL[offb];
      bl[j] = *(const short8*)&WlL[offb];
    }
    #pragma unroll
    for (int m = 0; m < 4; ++m){
      const int row = wr*64 + m*16 + l15;
      const int offa = row*32 + (lkq ^ (row & 3))*8;
      short8 ah = *(const short8*)&XhL[offa];
      short8 al = *(const short8*)&XlL[offa];
      #pragma unroll
      for (int j = 0; j < 4; ++j){
        acc[m][j] = __builtin_amdgcn_mfma_f32_16x16x32_bf16(ah, bh[j], acc[m][j], 0, 0, 0);
        acc[m][j] = __builtin_amdgcn_mfma_f32_16x16x32_bf16(ah, bl[j], acc[m][j], 0, 0, 0);
        acc[m][j] = __builtin_amdgcn_mfma_f32_16x16x32_bf16(al, bh[j], acc[m][j], 0, 0, 0);
      }
    }
  }

  // ---- epilogue: relu + bias, store y, fused score partials ----
  #pragma unroll
  for (int m = 0; m < 4; ++m){
    float prt[4] = {0.f, 0.f, 0.f, 0.f};
    #pragma unroll
    for (int j = 0; j < 4; ++j){
      const int col = wc*64 + j*16 + l15;
      const float bcol = bias[col];
      const float pcol = p[col];
      f32x4 a = acc[m][j];
      #pragma unroll
      for (int r = 0; r < 4; ++r){
        const int row = wr*64 + m*16 + lkq*4 + r;
        float y = fmaxf(a[r] + bcol, 0.f);
        yout[(size_t)(row0 + row)*128 + col] = y;
        prt[r] = fmaf(y, pcol, prt[r]);
      }
    }
    #pragma unroll
    for (int r = 0; r < 4; ++r){
      #pragma unroll
      for (int msk = 8; msk >= 1; msk >>= 1) prt[r] += __shfl_xor(prt[r], msk);
      if (l15 == 0) sbuf[(wr*64 + m*16 + lkq*4 + r)*2 + wc] = prt[r];
    }
  }
  __syncthreads();
  if (tid < 128) score[row0 + tid] = sbuf[tid*2] + sbuf[tid*2 + 1];
}

// ---------------- per-graph top-k via bitonic sort of (raw score desc, idx asc) ----------------
// writes alive_next (0/1) and scale (tanh for selected, 0 otherwise).

__global__ __launch_bounds__(1024) void topk_kernel(const float* __restrict__ score, const int* __restrict__ alive_cur,
      int* __restrict__ alive_next, float* __restrict__ scale, const float* __restrict__ p, int m){
  __shared__ float sv[1024];
  __shared__ int   si[1024];
  __shared__ float rnorm;
  int g = blockIdx.x, t = threadIdx.x;
  if (t < 64){
    float v0 = p[t], v1 = p[t + 64];
    float ss = v0*v0 + v1*v1;
    #pragma unroll
    for (int mm = 32; mm >= 1; mm >>= 1) ss += __shfl_xor(ss, mm);
    if (t == 0) rnorm = rsqrtf(ss);
  }
  int node = g*NPER + t;
  bool ok = alive_cur ? (alive_cur[node] != 0) : true;
  sv[t] = ok ? score[node] : -INFINITY;
  si[t] = node;
  alive_next[node] = 0;
  scale[node] = 0.f;
  __syncthreads();
  for (int size = 2; size <= 1024; size <<= 1){
    for (int stride = size >> 1; stride > 0; stride >>= 1){
      int j = t ^ stride;
      if (j > t){
        float vt = sv[t], vj = sv[j];
        int   it = si[t], ij = si[j];
        bool beforeTJ = (vt > vj) || (vt == vj && it < ij);  // t belongs first
        bool ascending = ((t & size) == 0);
        bool dosw = ascending ? !beforeTJ : beforeTJ;
        if (dosw){ sv[t] = vj; sv[j] = vt; si[t] = ij; si[j] = it; }
      }
      __syncthreads();
    }
  }
  if (t < m){
    int idx = si[t];
    alive_next[idx] = 1;
    scale[idx] = tanhf(sv[t] * rnorm);
  }
}

// ---------------- readout: per-graph masked max + mean of y*scale, accumulated into h ----------------

__global__ __launch_bounds__(1024) void readout_kernel(const float* __restrict__ y,
      const int* __restrict__ alive, const float* __restrict__ scale,
      float* __restrict__ h, int m){
  __shared__ float smx[32][33];
  __shared__ float ssm[32][33];
  int g = blockIdx.x;
  int fq = blockIdx.y;
  int t = threadIdx.x;
  int c  = t >> 5;         // node group 0..31
  int lf = t & 31;         // feature within quarter
  int f  = fq*32 + lf;
  int base = g*NPER;
  float mx = -INFINITY, sm = 0.f;
  #pragma unroll 4
  for (int i = 0; i < 32; ++i){
    int node = base + c + i*32;
    int al = alive[node];
    float v = y[(size_t)node*128 + f];
    float o = v * scale[node];          // scale==0 for dead -> o=0
    mx = al ? fmaxf(mx, o) : mx;
    sm += o;
  }
  smx[c][lf] = mx; ssm[c][lf] = sm;
  __syncthreads();
  for (int s = 16; s > 0; s >>= 1){
    if (c < s){
      smx[c][lf] = fmaxf(smx[c][lf], smx[c+s][lf]);
      ssm[c][lf] += ssm[c+s][lf];
    }
    __syncthreads();
  }
  if (c == 0){
    h[g*256 + f]       += smx[0][lf];
    h[g*256 + 128 + f] += ssm[0][lf] / (float)m;
  }
}

// ---------------- final MLP + log_softmax ----------------

__global__ __launch_bounds__(128) void final_kernel(const float* __restrict__ h,
      const float* __restrict__ l1w, const float* __restrict__ l1b,
      const float* __restrict__ l2w, const float* __restrict__ l2b,
      float* __restrict__ out){
  int g = blockIdx.x, t = threadIdx.x;
  __shared__ float hrow[256];
  __shared__ float red0[128], red1[128];
  hrow[t]       = h[g*256 + t];
  hrow[t + 128] = h[g*256 + 128 + t];
  __syncthreads();
  float a = l1b[t];
  for (int k = 0; k < 256; ++k) a = fmaf(hrow[k], l1w[k*128 + t], a);
  a = fmaxf(a, 0.f);
  red0[t] = a * l2w[t*2 + 0];
  red1[t] = a * l2w[t*2 + 1];
  __syncthreads();
  for (int s = 64; s > 0; s >>= 1){
    if (t < s){ red0[t] += red0[t + s]; red1[t] += red1[t + s]; }
    __syncthreads();
  }
  if (t == 0){
    float z0 = fmaxf(red0[0] + l2b[0], 0.f);
    float z1 = fmaxf(red1[0] + l2b[1], 0.f);
    float mz = fmaxf(z0, z1);
    float lse = mz + logf(expf(z0 - mz) + expf(z1 - mz));
    out[g*2 + 0] = z0 - lse;
    out[g*2 + 1] = z1 - lse;
  }
}

// ---------------- host ----------------

static inline size_t alignup(size_t x){ return (x + 255) & ~(size_t)255; }

extern "C" void kernel_launch(void* const* d_in, const int* in_sizes, int n_in,
                              void* d_out, int out_size, void* d_ws, size_t ws_size,
                              hipStream_t stream) {
  const float* x_in = (const float*)d_in[0];
  const int*   ei   = (const int*)d_in[1];
  const float* Wr[3] = {(const float*)d_in[3], (const float*)d_in[6], (const float*)d_in[9]};
  const float* Wn[3] = {(const float*)d_in[4], (const float*)d_in[7], (const float*)d_in[10]};
  const float* bs[3] = {(const float*)d_in[5], (const float*)d_in[8], (const float*)d_in[11]};
  const float* ps[3] = {(const float*)d_in[12], (const float*)d_in[13], (const float*)d_in[14]};
  const float* l1w = (const float*)d_in[15];
  const float* l1b = (const float*)d_in[16];
  const float* l2w = (const float*)d_in[17];
  const float* l2b = (const float*)d_in[18];
  float* out = (float*)d_out;

  char* w = (char*)d_ws;
  size_t o = 0;
  auto take = [&](size_t bytes) -> void* { void* p = w + o; o = alignup(o + bytes); return p; };
  int*   off    = (int*)  take((size_t)(NN + 1) * 4);
  int*   adj    = (int*)  take((size_t)NE * 4);
  int*   cnt    = (int*)  take((size_t)NN * 4);
  int*   loc    = (int*)  take((size_t)NN * 4);
  int*   cursor = (int*)  take((size_t)NN * 4);
  int*   bsum   = (int*)  take(64 * 4);
  int*   boff   = (int*)  take(64 * 4);
  int*   aliveA = (int*)  take((size_t)NN * 4);
  int*   aliveB = (int*)  take((size_t)NN * 4);
  float* scale  = (float*)take((size_t)NN * 4);
  float* score  = (float*)take((size_t)NN * 4);
  float* h      = (float*)take((size_t)NB * 256 * 4);
  unsigned short* WTh = (unsigned short*)take((size_t)128 * 256 * 2);
  unsigned short* WTl = (unsigned short*)take((size_t)128 * 256 * 2);
  float* A      = (float*)take((size_t)NN * 128 * 4);  // y buffer (odd levels)
  float* Bb     = (float*)take((size_t)NN * 128 * 4);  // y buffer (even levels)
  (void)ws_size; (void)n_in; (void)in_sizes; (void)out_size;

  // CSR build (by dst, storing src)
  hipMemsetAsync(cnt, 0, (size_t)NN * 4, stream);
  count_kernel<<<NE/256, 256, 0, stream>>>(ei, cnt);
  scan1_kernel<<<NN/1024, 1024, 0, stream>>>(cnt, loc, bsum);
  scan2_kernel<<<1, 64, 0, stream>>>(bsum, boff);
  scan3_kernel<<<NN/1024, 1024, 0, stream>>>(loc, boff, off, cursor);
  fill_kernel<<<NE/256, 256, 0, stream>>>(ei, cursor, adj);
  hipMemsetAsync(h, 0, (size_t)NB * 256 * 4, stream);

  const int MS[3] = {820, 656, 525};
  int* aliveCur = nullptr;
  int* aliveNext = aliveA;
  float* bufs[2] = {Bb, A};      // y_l lives in bufs[l&1]
  for (int l = 0; l < 3; ++l){
    const int Kx = (l == 0) ? 64 : 128;
    const int Ka = (l == 0) ? 64 : 128;
    const int Kcat = Kx + Ka;
    float* aggb = bufs[l & 1];               // gather dst + conv yout (aliased by design)
    wsplit_kernel<<<(Kcat*128 + 255)/256, 256, 0, stream>>>(Wr[l], Wn[l], Kx, Kcat, WTh, WTl);
    if (l == 0){
      gather_kernel<<<NN*64/256, 256, 0, stream>>>(x_in, 64, 64, off, adj, aggb, nullptr, nullptr);
      conv_kernel<<<NN/128, 256, 0, stream>>>(x_in, 64, Kx/32, aggb, Ka/32, WTh, WTl, Kcat,
                                              bs[0], ps[0], nullptr, aggb, score);
    } else {
      const float* ysrc = bufs[(l - 1) & 1]; // previous level's y
      gather_kernel<<<NN*64/256, 256, 0, stream>>>(ysrc, 128, 128, off, adj, aggb, aliveCur, scale);
      conv_kernel<<<NN/128, 256, 0, stream>>>(ysrc, 128, Kx/32, aggb, Ka/32, WTh, WTl, Kcat,
                                              bs[l], ps[l], scale, aggb, score);
    }
    topk_kernel<<<NB, 1024, 0, stream>>>(score, aliveCur, aliveNext, scale, ps[l], MS[l]);
    readout_kernel<<<dim3(NB, 4), 1024, 0, stream>>>(aggb, aliveNext, scale, h, MS[l]);
    aliveCur = aliveNext;
    aliveNext = (l == 0) ? aliveB : aliveA;
  }
  final_kernel<<<NB, 128, 0, stream>>>(h, l1w, l1b, l2w, l2b, out);
}

// Round 11
// 327.389 us; speedup vs baseline: 1.6073x; 1.1079x over previous
//
#include <hip/hip_runtime.h>
#include <hip/hip_bf16.h>
#include <math.h>

#define NN   65536      // total nodes
#define NPER 1024       // nodes per graph
#define NE   1048576    // edges
#define NB   64         // graphs

typedef __attribute__((ext_vector_type(8))) short short8;   // 8 bf16 = 4 VGPR
typedef __attribute__((ext_vector_type(4))) float f32x4;    // MFMA acc

// ---------------- CSR build ----------------

__global__ __launch_bounds__(256) void count_kernel(const int* __restrict__ ei, int* __restrict__ cnt){
  int e = blockIdx.x*256 + threadIdx.x;
  if (e < NE) atomicAdd(&cnt[ei[NE + e]], 1);
}

__global__ __launch_bounds__(1024) void scan1_kernel(const int* __restrict__ cnt,
      int* __restrict__ loc, int* __restrict__ bsum){
  __shared__ int wsum[16];
  int t = threadIdx.x;
  int i = blockIdx.x*1024 + t;
  int lane = t & 63, wid = t >> 6;
  int v = cnt[i];
  int s = v;
  #pragma unroll
  for (int d = 1; d < 64; d <<= 1){
    int src = (lane >= d) ? (lane - d) : lane;
    int u = __shfl(s, src);
    if (lane >= d) s += u;
  }
  if (lane == 63) wsum[wid] = s;
  __syncthreads();
  if (wid == 0){
    int ws = (lane < 16) ? wsum[lane] : 0;
    #pragma unroll
    for (int d = 1; d < 16; d <<= 1){
      int src = (lane >= d) ? (lane - d) : lane;
      int u = __shfl(ws, src);
      if (lane >= d) ws += u;
    }
    if (lane < 16) wsum[lane] = ws;
  }
  __syncthreads();
  int base = (wid > 0) ? wsum[wid - 1] : 0;
  loc[i] = base + s - v;                 // exclusive within block
  if (t == 1023) bsum[blockIdx.x] = base + s;
}

__global__ __launch_bounds__(64) void scan2_kernel(const int* __restrict__ bsum, int* __restrict__ boff){
  int t = threadIdx.x;
  int v = bsum[t];
  int s = v;
  #pragma unroll
  for (int d = 1; d < 64; d <<= 1){
    int src = (t >= d) ? (t - d) : t;
    int u = __shfl(s, src);
    if (t >= d) s += u;
  }
  boff[t] = s - v;
}

__global__ __launch_bounds__(1024) void scan3_kernel(const int* __restrict__ loc, const int* __restrict__ boff,
      int* __restrict__ off, int* __restrict__ cursor){
  int i = blockIdx.x*1024 + threadIdx.x;
  int v = loc[i] + boff[blockIdx.x];
  off[i] = v;
  cursor[i] = v;
  if (i == NN - 1) off[NN] = NE;
}

__global__ __launch_bounds__(256) void fill_kernel(const int* __restrict__ ei, int* cursor, int* __restrict__ adj){
  int e = blockIdx.x*256 + threadIdx.x;
  if (e < NE){
    int pos = atomicAdd(&cursor[ei[NE + e]], 1);
    adj[pos] = ei[e];
  }
}

// ---------------- aggregation: agg[w] = sum_e scale[src_e] * y[src_e] ----------------
// one wave per dst node, float4 per lane, XCD-chunked swizzle. Branch-free: edge index
// clamped to s1-1, tail/dead contributions multiplied by 0. scale and row loads issue
// in parallel (both depend only on adj) -> 2-deep chain, 16 edges/iter in flight.

__global__ __launch_bounds__(256) void gather_kernel(const float* __restrict__ x, int stride, int F,
      const int* __restrict__ off, const int* __restrict__ adj, float* __restrict__ agg,
      const int* __restrict__ alive, const float* __restrict__ scale){
  int bid = blockIdx.x;
  bid = (bid & 7) * (gridDim.x >> 3) + (bid >> 3);   // round-robin XCD -> contiguous chunks
  int w = (bid*256 + (int)threadIdx.x) >> 6;
  int lane = threadIdx.x & 63;
  if (w >= NN) return;
  if (alive && !alive[w]) return;
  int s0 = off[w], s1 = off[w+1];
  if (F == 64){
    int sub = lane >> 4;            // edge-group 0..3
    int fl  = (lane & 15) * 4;      // features fl..fl+3
    float4 a[4];
    #pragma unroll
    for (int i = 0; i < 4; ++i) a[i] = make_float4(0.f,0.f,0.f,0.f);
    for (int e = s0; e < s1; e += 16){
      int ss[4]; float tv[4];
      #pragma unroll
      for (int i = 0; i < 4; ++i){
        int ei = e + 4*i + sub;
        bool okE = ei < s1;
        ss[i] = adj[okE ? ei : (s1 - 1)];
        tv[i] = okE ? 1.f : 0.f;
      }
      #pragma unroll
      for (int i = 0; i < 4; ++i){
        float4 v = *(const float4*)&x[(size_t)ss[i]*stride + fl];
        a[i].x = fmaf(v.x, tv[i], a[i].x);
        a[i].y = fmaf(v.y, tv[i], a[i].y);
        a[i].z = fmaf(v.z, tv[i], a[i].z);
        a[i].w = fmaf(v.w, tv[i], a[i].w);
      }
    }
    float4 r;
    r.x = (a[0].x + a[1].x) + (a[2].x + a[3].x);
    r.y = (a[0].y + a[1].y) + (a[2].y + a[3].y);
    r.z = (a[0].z + a[1].z) + (a[2].z + a[3].z);
    r.w = (a[0].w + a[1].w) + (a[2].w + a[3].w);
    #pragma unroll
    for (int m = 16; m <= 32; m <<= 1){
      r.x += __shfl_xor(r.x, m);
      r.y += __shfl_xor(r.y, m);
      r.z += __shfl_xor(r.z, m);
      r.w += __shfl_xor(r.w, m);
    }
    if (lane < 16) *(float4*)&agg[(size_t)w*128 + fl] = r;
  } else {
    int sub = lane >> 5;            // edge-group 0..1
    int fl  = (lane & 31) * 4;
    float4 a[8];
    #pragma unroll
    for (int i = 0; i < 8; ++i) a[i] = make_float4(0.f,0.f,0.f,0.f);
    for (int e = s0; e < s1; e += 16){
      int ss[8]; float tv[8];
      #pragma unroll
      for (int i = 0; i < 8; ++i){
        int ei = e + 2*i + sub;
        bool okE = ei < s1;
        int s = adj[okE ? ei : (s1 - 1)];
        ss[i] = s;
        float t = scale[s];                 // dead src -> 0, kills tail & dead rows
        tv[i] = okE ? t : 0.f;
      }
      #pragma unroll
      for (int i = 0; i < 8; ++i){
        float4 v = *(const float4*)&x[(size_t)ss[i]*stride + fl];
        a[i].x = fmaf(v.x, tv[i], a[i].x);
        a[i].y = fmaf(v.y, tv[i], a[i].y);
        a[i].z = fmaf(v.z, tv[i], a[i].z);
        a[i].w = fmaf(v.w, tv[i], a[i].w);
      }
    }
    float4 r;
    r.x = (a[0].x+a[1].x)+(a[2].x+a[3].x)+((a[4].x+a[5].x)+(a[6].x+a[7].x));
    r.y = (a[0].y+a[1].y)+(a[2].y+a[3].y)+((a[4].y+a[5].y)+(a[6].y+a[7].y));
    r.z = (a[0].z+a[1].z)+(a[2].z+a[3].z)+((a[4].z+a[5].z)+(a[6].z+a[7].z));
    r.w = (a[0].w+a[1].w)+(a[2].w+a[3].w)+((a[4].w+a[5].w)+(a[6].w+a[7].w));
    r.x += __shfl_xor(r.x, 32);
    r.y += __shfl_xor(r.y, 32);
    r.z += __shfl_xor(r.z, 32);
    r.w += __shfl_xor(r.w, 32);
    if (lane < 32) *(float4*)&agg[(size_t)w*128 + fl] = r;
  }
}

// ---------------- W prep: Wcat = [Wr;Wn] -> transposed bf16 hi/lo WT[col][k] ----------------

__global__ __launch_bounds__(256) void wsplit_kernel(const float* __restrict__ Wr, const float* __restrict__ Wn,
      int Kx, int Kcat, unsigned short* __restrict__ WTh, unsigned short* __restrict__ WTl){
  int idx = blockIdx.x*256 + threadIdx.x;
  if (idx >= Kcat*128) return;
  int c = idx & 127, k = idx >> 7;
  float w = (k < Kx) ? Wr[k*128 + c] : Wn[(k - Kx)*128 + c];
  __hip_bfloat16 h = __float2bfloat16(w);
  float hf = __bfloat162float(h);
  __hip_bfloat16 l = __float2bfloat16(w - hf);
  WTh[(size_t)c*Kcat + k] = reinterpret_cast<unsigned short&>(h);
  WTl[(size_t)c*Kcat + k] = reinterpret_cast<unsigned short&>(l);
}

// ---------------- conv via bf16x3 MFMA: y = relu((scale.x)@Wr + agg@Wn + b), score = y.p ----
// 128x128 tile, 256 threads = 2x2 waves of 64x64, mfma_f32_16x16x32_bf16, split product
// Xh*Wh + Xh*Wl + Xl*Wh. X rows scaled by scaleX[row] (tanh-fold) during self-term staging.
// NOTE: yout aliases aggb: staging reads of a block's own rows all complete
// before the last barrier; epilogue writes after.

__global__ __launch_bounds__(256, 2) void conv_kernel(const float* __restrict__ xsrc, int strideX, int ntx,
      const float* aggb, int nta,
      const unsigned short* __restrict__ WTh, const unsigned short* __restrict__ WTl, int Kcat,
      const float* __restrict__ bias, const float* __restrict__ p, const float* __restrict__ scaleX,
      float* yout, float* __restrict__ score){
  __shared__ unsigned short XhL[128*32], XlL[128*32];
  __shared__ unsigned short WhL[128*32], WlL[128*32];
  __shared__ float sbuf[128*2];
  const int tid = threadIdx.x;
  const int row0 = blockIdx.x * 128;
  const int srow = tid & 127;          // staging row (X) / col (W)
  const int shalf = tid >> 7;          // staging k-half (16 k each)
  const int lane = tid & 63;
  const int wid = tid >> 6;            // 4 waves: 2x2
  const int wr = wid >> 1, wc = wid & 1;
  const int l15 = lane & 15, lkq = lane >> 4;

  const float xscale = scaleX ? scaleX[row0 + srow] : 1.f;

  f32x4 acc[4][4];
  #pragma unroll
  for (int m = 0; m < 4; ++m)
    #pragma unroll
    for (int j = 0; j < 4; ++j)
      acc[m][j] = (f32x4){0.f, 0.f, 0.f, 0.f};

  const int nt = ntx + nta;
  for (int t = 0; t < nt; ++t){
    __syncthreads();                   // previous tile's compute done
    // ---- stage X (fp32 -> scale -> bf16 hi/lo) ----
    {
      const float* Xs   = (t < ntx) ? xsrc : aggb;
      const int stride  = (t < ntx) ? strideX : 128;
      const int kc      = (t < ntx) ? t*32 : (t - ntx)*32;
      const float sc    = (t < ntx) ? xscale : 1.f;
      #pragma unroll
      for (int kq2 = 0; kq2 < 2; ++kq2){
        const int kq = shalf*2 + kq2;
        const float* xp = Xs + (size_t)(row0 + srow)*stride + kc + kq*8;
        float4 v0 = *(const float4*)(xp);
        float4 v1 = *(const float4*)(xp + 4);
        float vv[8] = {v0.x*sc, v0.y*sc, v0.z*sc, v0.w*sc,
                       v1.x*sc, v1.y*sc, v1.z*sc, v1.w*sc};
        short8 hs, ls;
        #pragma unroll
        for (int q = 0; q < 8; ++q){
          __hip_bfloat16 h = __float2bfloat16(vv[q]);
          float hf = __bfloat162float(h);
          __hip_bfloat16 lo = __float2bfloat16(vv[q] - hf);
          hs[q] = reinterpret_cast<short&>(h);
          ls[q] = reinterpret_cast<short&>(lo);
        }
        const int kqph = kq ^ (srow & 3);
        *(short8*)&XhL[srow*32 + kqph*8] = hs;
        *(short8*)&XlL[srow*32 + kqph*8] = ls;
      }
      // ---- stage W (already bf16 hi/lo, [col][k]) ----
      const int kcw = t*32;
      #pragma unroll
      for (int kq2 = 0; kq2 < 2; ++kq2){
        const int kq = shalf*2 + kq2;
        short8 h = *(const short8*)&WTh[(size_t)srow*Kcat + kcw + kq*8];
        short8 l = *(const short8*)&WTl[(size_t)srow*Kcat + kcw + kq*8];
        const int kqph = kq ^ (srow & 3);
        *(short8*)&WhL[srow*32 + kqph*8] = h;
        *(short8*)&WlL[srow*32 + kqph*8] = l;
      }
    }
    __syncthreads();
    // ---- MFMA: wave (wr,wc) computes rows wr*64..+63 x cols wc*64..+63 ----
    short8 bh[4], bl[4];
    #pragma unroll
    for (int j = 0; j < 4; ++j){
      const int col = wc*64 + j*16 + l15;
      const int offb = col*32 + (lkq ^ (col & 3))*8;
      bh[j] = *(const short8*)&WhL[offb];
      bl[j] = *(const short8*)&WlL[offb];
    }
    #pragma unroll
    for (int m = 0; m < 4; ++m){
      const int row = wr*64 + m*16 + l15;
      const int offa = row*32 + (lkq ^ (row & 3))*8;
      short8 ah = *(const short8*)&XhL[offa];
      short8 al = *(const short8*)&XlL[offa];
      #pragma unroll
      for (int j = 0; j < 4; ++j){
        acc[m][j] = __builtin_amdgcn_mfma_f32_16x16x32_bf16(ah, bh[j], acc[m][j], 0, 0, 0);
        acc[m][j] = __builtin_amdgcn_mfma_f32_16x16x32_bf16(ah, bl[j], acc[m][j], 0, 0, 0);
        acc[m][j] = __builtin_amdgcn_mfma_f32_16x16x32_bf16(al, bh[j], acc[m][j], 0, 0, 0);
      }
    }
  }

  // ---- epilogue: relu + bias, store y, fused score partials ----
  #pragma unroll
  for (int m = 0; m < 4; ++m){
    float prt[4] = {0.f, 0.f, 0.f, 0.f};
    #pragma unroll
    for (int j = 0; j < 4; ++j){
      const int col = wc*64 + j*16 + l15;
      const float bcol = bias[col];
      const float pcol = p[col];
      f32x4 a = acc[m][j];
      #pragma unroll
      for (int r = 0; r < 4; ++r){
        const int row = wr*64 + m*16 + lkq*4 + r;
        float y = fmaxf(a[r] + bcol, 0.f);
        yout[(size_t)(row0 + row)*128 + col] = y;
        prt[r] = fmaf(y, pcol, prt[r]);
      }
    }
    #pragma unroll
    for (int r = 0; r < 4; ++r){
      #pragma unroll
      for (int msk = 8; msk >= 1; msk >>= 1) prt[r] += __shfl_xor(prt[r], msk);
      if (l15 == 0) sbuf[(wr*64 + m*16 + lkq*4 + r)*2 + wc] = prt[r];
    }
  }
  __syncthreads();
  if (tid < 128) score[row0 + tid] = sbuf[tid*2] + sbuf[tid*2 + 1];
}

// ---------------- per-graph top-k via hybrid bitonic sort (raw score desc, idx asc) ----------------
// registers + shfl_xor for strides<64, LDS exchange only for strides>=64 (10 steps, 20 barriers).
// Identical network/tie-break to the full-LDS version. Writes alive_next and scale (tanh / 0).

__global__ __launch_bounds__(1024) void topk_kernel(const float* __restrict__ score, const int* __restrict__ alive_cur,
      int* __restrict__ alive_next, float* __restrict__ scale, const float* __restrict__ p, int m){
  __shared__ float lv[1024];
  __shared__ int   li[1024];
  __shared__ float rnorm;
  const int g = blockIdx.x, t = threadIdx.x;
  if (t < 64){
    float v0 = p[t], v1 = p[t + 64];
    float ss = v0*v0 + v1*v1;
    #pragma unroll
    for (int mm = 32; mm >= 1; mm >>= 1) ss += __shfl_xor(ss, mm);
    if (t == 0) rnorm = rsqrtf(ss);
  }
  const int node = g*NPER + t;
  bool ok = alive_cur ? (alive_cur[node] != 0) : true;
  float v = ok ? score[node] : -INFINITY;
  int idx = node;
  alive_next[node] = 0;
  scale[node] = 0.f;

  auto cex_shfl = [&](int stride, bool dirUp){
    float vj = __shfl_xor(v, stride);
    int   ij = __shfl_xor(idx, stride);
    bool iAmLow = (t & stride) == 0;
    bool mineFirst = (v > vj) || (v == vj && idx < ij);   // desc score, asc idx
    bool takeMine = ((dirUp == iAmLow) == mineFirst);
    v   = takeMine ? v   : vj;
    idx = takeMine ? idx : ij;
  };
  auto cex_lds = [&](int stride, bool dirUp){
    __syncthreads();
    lv[t] = v; li[t] = idx;
    __syncthreads();
    float vj = lv[t ^ stride];
    int   ij = li[t ^ stride];
    bool iAmLow = (t & stride) == 0;
    bool mineFirst = (v > vj) || (v == vj && idx < ij);
    bool takeMine = ((dirUp == iAmLow) == mineFirst);
    v   = takeMine ? v   : vj;
    idx = takeMine ? idx : ij;
  };

  #pragma unroll
  for (int size = 2; size <= 64; size <<= 1){
    const bool dirUp = (t & size) == 0;
    for (int stride = size >> 1; stride >= 1; stride >>= 1)
      cex_shfl(stride, dirUp);
  }
  #pragma unroll
  for (int size = 128; size <= 1024; size <<= 1){
    const bool dirUp = (t & size) == 0;
    for (int stride = size >> 1; stride >= 64; stride >>= 1)
      cex_lds(stride, dirUp);
    for (int stride = 32; stride >= 1; stride >>= 1)
      cex_shfl(stride, dirUp);
  }

  if (t < m){
    alive_next[idx] = 1;
    scale[idx] = tanhf(v * rnorm);
  }
}

// ---------------- readout: per-graph masked max + mean of y*scale, accumulated into h ----------------

__global__ __launch_bounds__(1024) void readout_kernel(const float* __restrict__ y,
      const int* __restrict__ alive, const float* __restrict__ scale,
      float* __restrict__ h, int m){
  __shared__ float smx[32][33];
  __shared__ float ssm[32][33];
  int g = blockIdx.x;
  int fq = blockIdx.y;
  int t = threadIdx.x;
  int c  = t >> 5;         // node group 0..31
  int lf = t & 31;         // feature within quarter
  int f  = fq*32 + lf;
  int base = g*NPER;
  float mx = -INFINITY, sm = 0.f;
  #pragma unroll 4
  for (int i = 0; i < 32; ++i){
    int node = base + c + i*32;
    int al = alive[node];
    float v = y[(size_t)node*128 + f];
    float o = v * scale[node];          // scale==0 for dead -> o=0
    mx = al ? fmaxf(mx, o) : mx;
    sm += o;
  }
  smx[c][lf] = mx; ssm[c][lf] = sm;
  __syncthreads();
  for (int s = 16; s > 0; s >>= 1){
    if (c < s){
      smx[c][lf] = fmaxf(smx[c][lf], smx[c+s][lf]);
      ssm[c][lf] += ssm[c+s][lf];
    }
    __syncthreads();
  }
  if (c == 0){
    h[g*256 + f]       += smx[0][lf];
    h[g*256 + 128 + f] += ssm[0][lf] / (float)m;
  }
}

// ---------------- final MLP + log_softmax ----------------

__global__ __launch_bounds__(128) void final_kernel(const float* __restrict__ h,
      const float* __restrict__ l1w, const float* __restrict__ l1b,
      const float* __restrict__ l2w, const float* __restrict__ l2b,
      float* __restrict__ out){
  int g = blockIdx.x, t = threadIdx.x;
  __shared__ float hrow[256];
  __shared__ float red0[128], red1[128];
  hrow[t]       = h[g*256 + t];
  hrow[t + 128] = h[g*256 + 128 + t];
  __syncthreads();
  float a = l1b[t];
  for (int k = 0; k < 256; ++k) a = fmaf(hrow[k], l1w[k*128 + t], a);
  a = fmaxf(a, 0.f);
  red0[t] = a * l2w[t*2 + 0];
  red1[t] = a * l2w[t*2 + 1];
  __syncthreads();
  for (int s = 64; s > 0; s >>= 1){
    if (t < s){ red0[t] += red0[t + s]; red1[t] += red1[t + s]; }
    __syncthreads();
  }
  if (t == 0){
    float z0 = fmaxf(red0[0] + l2b[0], 0.f);
    float z1 = fmaxf(red1[0] + l2b[1], 0.f);
    float mz = fmaxf(z0, z1);
    float lse = mz + logf(expf(z0 - mz) + expf(z1 - mz));
    out[g*2 + 0] = z0 - lse;
    out[g*2 + 1] = z1 - lse;
  }
}

// ---------------- host ----------------

static inline size_t alignup(size_t x){ return (x + 255) & ~(size_t)255; }

extern "C" void kernel_launch(void* const* d_in, const int* in_sizes, int n_in,
                              void* d_out, int out_size, void* d_ws, size_t ws_size,
                              hipStream_t stream) {
  const float* x_in = (const float*)d_in[0];
  const int*   ei   = (const int*)d_in[1];
  const float* Wr[3] = {(const float*)d_in[3], (const float*)d_in[6], (const float*)d_in[9]};
  const float* Wn[3] = {(const float*)d_in[4], (const float*)d_in[7], (const float*)d_in[10]};
  const float* bs[3] = {(const float*)d_in[5], (const float*)d_in[8], (const float*)d_in[11]};
  const float* ps[3] = {(const float*)d_in[12], (const float*)d_in[13], (const float*)d_in[14]};
  const float* l1w = (const float*)d_in[15];
  const float* l1b = (const float*)d_in[16];
  const float* l2w = (const float*)d_in[17];
  const float* l2b = (const float*)d_in[18];
  float* out = (float*)d_out;

  char* w = (char*)d_ws;
  size_t o = 0;
  auto take = [&](size_t bytes) -> void* { void* p = w + o; o = alignup(o + bytes); return p; };
  int*   off    = (int*)  take((size_t)(NN + 1) * 4);
  int*   adj    = (int*)  take((size_t)NE * 4);
  int*   cnt    = (int*)  take((size_t)NN * 4);
  int*   loc    = (int*)  take((size_t)NN * 4);
  int*   cursor = (int*)  take((size_t)NN * 4);
  int*   bsum   = (int*)  take(64 * 4);
  int*   boff   = (int*)  take(64 * 4);
  int*   aliveA = (int*)  take((size_t)NN * 4);
  int*   aliveB = (int*)  take((size_t)NN * 4);
  float* scale  = (float*)take((size_t)NN * 4);
  float* score  = (float*)take((size_t)NN * 4);
  float* h      = (float*)take((size_t)NB * 256 * 4);
  unsigned short* WTh = (unsigned short*)take((size_t)128 * 256 * 2);
  unsigned short* WTl = (unsigned short*)take((size_t)128 * 256 * 2);
  float* A      = (float*)take((size_t)NN * 128 * 4);  // y buffer (odd levels)
  float* Bb     = (float*)take((size_t)NN * 128 * 4);  // y buffer (even levels)
  (void)ws_size; (void)n_in; (void)in_sizes; (void)out_size;

  // CSR build (by dst, storing src)
  hipMemsetAsync(cnt, 0, (size_t)NN * 4, stream);
  count_kernel<<<NE/256, 256, 0, stream>>>(ei, cnt);
  scan1_kernel<<<NN/1024, 1024, 0, stream>>>(cnt, loc, bsum);
  scan2_kernel<<<1, 64, 0, stream>>>(bsum, boff);
  scan3_kernel<<<NN/1024, 1024, 0, stream>>>(loc, boff, off, cursor);
  fill_kernel<<<NE/256, 256, 0, stream>>>(ei, cursor, adj);
  hipMemsetAsync(h, 0, (size_t)NB * 256 * 4, stream);

  const int MS[3] = {820, 656, 525};
  int* aliveCur = nullptr;
  int* aliveNext = aliveA;
  float* bufs[2] = {Bb, A};      // y_l lives in bufs[l&1]
  for (int l = 0; l < 3; ++l){
    const int Kx = (l == 0) ? 64 : 128;
    const int Ka = (l == 0) ? 64 : 128;
    const int Kcat = Kx + Ka;
    float* aggb = bufs[l & 1];               // gather dst + conv yout (aliased by design)
    wsplit_kernel<<<(Kcat*128 + 255)/256, 256, 0, stream>>>(Wr[l], Wn[l], Kx, Kcat, WTh, WTl);
    if (l == 0){
      gather_kernel<<<NN*64/256, 256, 0, stream>>>(x_in, 64, 64, off, adj, aggb, nullptr, nullptr);
      conv_kernel<<<NN/128, 256, 0, stream>>>(x_in, 64, Kx/32, aggb, Ka/32, WTh, WTl, Kcat,
                                              bs[0], ps[0], nullptr, aggb, score);
    } else {
      const float* ysrc = bufs[(l - 1) & 1]; // previous level's y
      gather_kernel<<<NN*64/256, 256, 0, stream>>>(ysrc, 128, 128, off, adj, aggb, aliveCur, scale);
      conv_kernel<<<NN/128, 256, 0, stream>>>(ysrc, 128, Kx/32, aggb, Ka/32, WTh, WTl, Kcat,
                                              bs[l], ps[l], scale, aggb, score);
    }
    topk_kernel<<<NB, 1024, 0, stream>>>(score, aliveCur, aliveNext, scale, ps[l], MS[l]);
    readout_kernel<<<dim3(NB, 4), 1024, 0, stream>>>(aggb, aliveNext, scale, h, MS[l]);
    aliveCur = aliveNext;
    aliveNext = (l == 0) ? aliveB : aliveA;
  }
  final_kernel<<<NB, 128, 0, stream>>>(h, l1w, l1b, l2w, l2b, out);
}

// Round 12
// 317.021 us; speedup vs baseline: 1.6598x; 1.0327x over previous
//
#include <hip/hip_runtime.h>
#include <hip/hip_bf16.h>
#include <math.h>

#define NN   65536      // total nodes
#define NPER 1024       // nodes per graph
#define NE   1048576    // edges
#define NB   64         // graphs

typedef __attribute__((ext_vector_type(8))) short short8;   // 8 bf16 = 4 VGPR
typedef __attribute__((ext_vector_type(4))) float f32x4;    // MFMA acc

// ---------------- CSR build ----------------

__global__ __launch_bounds__(256) void count_kernel(const int* __restrict__ ei, int* __restrict__ cnt){
  int e = blockIdx.x*256 + threadIdx.x;
  if (e < NE) atomicAdd(&cnt[ei[NE + e]], 1);
}

__global__ __launch_bounds__(1024) void scan1_kernel(const int* __restrict__ cnt,
      int* __restrict__ loc, int* __restrict__ bsum){
  __shared__ int wsum[16];
  int t = threadIdx.x;
  int i = blockIdx.x*1024 + t;
  int lane = t & 63, wid = t >> 6;
  int v = cnt[i];
  int s = v;
  #pragma unroll
  for (int d = 1; d < 64; d <<= 1){
    int src = (lane >= d) ? (lane - d) : lane;
    int u = __shfl(s, src);
    if (lane >= d) s += u;
  }
  if (lane == 63) wsum[wid] = s;
  __syncthreads();
  if (wid == 0){
    int ws = (lane < 16) ? wsum[lane] : 0;
    #pragma unroll
    for (int d = 1; d < 16; d <<= 1){
      int src = (lane >= d) ? (lane - d) : lane;
      int u = __shfl(ws, src);
      if (lane >= d) ws += u;
    }
    if (lane < 16) wsum[lane] = ws;
  }
  __syncthreads();
  int base = (wid > 0) ? wsum[wid - 1] : 0;
  loc[i] = base + s - v;                 // exclusive within block
  if (t == 1023) bsum[blockIdx.x] = base + s;
}

__global__ __launch_bounds__(64) void scan2_kernel(const int* __restrict__ bsum, int* __restrict__ boff){
  int t = threadIdx.x;
  int v = bsum[t];
  int s = v;
  #pragma unroll
  for (int d = 1; d < 64; d <<= 1){
    int src = (t >= d) ? (t - d) : t;
    int u = __shfl(s, src);
    if (t >= d) s += u;
  }
  boff[t] = s - v;
}

__global__ __launch_bounds__(1024) void scan3_kernel(const int* __restrict__ loc, const int* __restrict__ boff,
      int* __restrict__ off, int* __restrict__ cursor){
  int i = blockIdx.x*1024 + threadIdx.x;
  int v = loc[i] + boff[blockIdx.x];
  off[i] = v;
  cursor[i] = v;
  if (i == NN - 1) off[NN] = NE;
}

__global__ __launch_bounds__(256) void fill_kernel(const int* __restrict__ ei, int* cursor, int* __restrict__ adj){
  int e = blockIdx.x*256 + threadIdx.x;
  if (e < NE){
    int pos = atomicAdd(&cursor[ei[NE + e]], 1);
    adj[pos] = ei[e];
  }
}

// ---------------- per-level edge compaction ----------------
// wave per dst node: keep only edges with scale[src]!=0, fuse scale value.
// Removing exact-zero addends is bit-exact for the downstream sum.

__global__ __launch_bounds__(256) void compact_kernel(const int* __restrict__ off, const int* __restrict__ adj,
      const float* __restrict__ scale, const int* __restrict__ alive,
      int* __restrict__ adj2, float* __restrict__ scl2, int* __restrict__ deg2){
  int w = (blockIdx.x*256 + (int)threadIdx.x) >> 6;
  int lane = threadIdx.x & 63;
  if (w >= NN) return;
  if (!alive[w]){ if (lane == 0) deg2[w] = 0; return; }
  int s0 = off[w], s1 = off[w+1];
  int base = s0;
  for (int e0 = s0; e0 < s1; e0 += 64){
    int e = e0 + lane;
    bool okE = e < s1;
    int s = adj[okE ? e : (s1 - 1)];
    float t = scale[s];
    bool keep = okE && (t != 0.f);
    unsigned long long m = __ballot(keep);
    int pos = base + __popcll(m & ((1ull << lane) - 1ull));
    if (keep){ adj2[pos] = s; scl2[pos] = t; }
    base += __popcll(m);
  }
  if (lane == 0) deg2[w] = base - s0;
}

// ---------------- aggregation: agg[w] = sum_e scl_e * y[src_e] ----------------
// one wave per dst node, float4 per lane, XCD-chunked swizzle, 8-edge granularity
// (measured better slot efficiency than 16 at deg~Poisson(16)). Branch-free clamp.
// F==64 (level 0): adj raw, scl==null (weight 1). F==128: compacted adj/scl, s1 from deg2.

__global__ __launch_bounds__(256) void gather_kernel(const float* __restrict__ x, int stride, int F,
      const int* __restrict__ off, const int* __restrict__ adj, const float* __restrict__ scl,
      const int* __restrict__ deg2, float* __restrict__ agg, const int* __restrict__ alive){
  int bid = blockIdx.x;
  bid = (bid & 7) * (gridDim.x >> 3) + (bid >> 3);   // round-robin XCD -> contiguous chunks
  int w = (bid*256 + (int)threadIdx.x) >> 6;
  int lane = threadIdx.x & 63;
  if (w >= NN) return;
  if (alive && !alive[w]) return;
  int s0 = off[w];
  int s1 = deg2 ? (s0 + deg2[w]) : off[w+1];
  if (F == 64){
    int sub = lane >> 4;            // edge-group 0..3
    int fl  = (lane & 15) * 4;      // features fl..fl+3
    float4 a0 = make_float4(0.f,0.f,0.f,0.f), a1 = a0;
    if (s1 > s0){
      for (int e = s0; e < s1; e += 8){
        int e0 = e + sub, e1 = e + 4 + sub;
        bool ok0 = e0 < s1, ok1 = e1 < s1;
        int sA = adj[ok0 ? e0 : (s1 - 1)];
        int sB = adj[ok1 ? e1 : (s1 - 1)];
        float t0 = ok0 ? 1.f : 0.f, t1 = ok1 ? 1.f : 0.f;
        float4 vA = *(const float4*)&x[(size_t)sA*stride + fl];
        float4 vB = *(const float4*)&x[(size_t)sB*stride + fl];
        a0.x = fmaf(vA.x, t0, a0.x); a0.y = fmaf(vA.y, t0, a0.y);
        a0.z = fmaf(vA.z, t0, a0.z); a0.w = fmaf(vA.w, t0, a0.w);
        a1.x = fmaf(vB.x, t1, a1.x); a1.y = fmaf(vB.y, t1, a1.y);
        a1.z = fmaf(vB.z, t1, a1.z); a1.w = fmaf(vB.w, t1, a1.w);
      }
    }
    a0.x += a1.x; a0.y += a1.y; a0.z += a1.z; a0.w += a1.w;
    #pragma unroll
    for (int m = 16; m <= 32; m <<= 1){
      a0.x += __shfl_xor(a0.x, m);
      a0.y += __shfl_xor(a0.y, m);
      a0.z += __shfl_xor(a0.z, m);
      a0.w += __shfl_xor(a0.w, m);
    }
    if (lane < 16) *(float4*)&agg[(size_t)w*128 + fl] = a0;
  } else {
    int sub = lane >> 5;            // edge-group 0..1
    int fl  = (lane & 31) * 4;
    float4 a[4];
    #pragma unroll
    for (int i = 0; i < 4; ++i) a[i] = make_float4(0.f,0.f,0.f,0.f);
    if (s1 > s0){
      for (int e = s0; e < s1; e += 8){
        int ss[4]; float tv[4];
        #pragma unroll
        for (int i = 0; i < 4; ++i){
          int ei = e + 2*i + sub;
          bool okE = ei < s1;
          int ii = okE ? ei : (s1 - 1);
          ss[i] = adj[ii];
          tv[i] = okE ? scl[ii] : 0.f;
        }
        #pragma unroll
        for (int i = 0; i < 4; ++i){
          float4 v = *(const float4*)&x[(size_t)ss[i]*stride + fl];
          a[i].x = fmaf(v.x, tv[i], a[i].x);
          a[i].y = fmaf(v.y, tv[i], a[i].y);
          a[i].z = fmaf(v.z, tv[i], a[i].z);
          a[i].w = fmaf(v.w, tv[i], a[i].w);
        }
      }
    }
    float4 r;
    r.x = (a[0].x + a[1].x) + (a[2].x + a[3].x);
    r.y = (a[0].y + a[1].y) + (a[2].y + a[3].y);
    r.z = (a[0].z + a[1].z) + (a[2].z + a[3].z);
    r.w = (a[0].w + a[1].w) + (a[2].w + a[3].w);
    r.x += __shfl_xor(r.x, 32);
    r.y += __shfl_xor(r.y, 32);
    r.z += __shfl_xor(r.z, 32);
    r.w += __shfl_xor(r.w, 32);
    if (lane < 32) *(float4*)&agg[(size_t)w*128 + fl] = r;
  }
}

// ---------------- W prep: Wcat = [Wr;Wn] -> transposed bf16 hi/lo WT[col][k] ----------------

__global__ __launch_bounds__(256) void wsplit_kernel(const float* __restrict__ Wr, const float* __restrict__ Wn,
      int Kx, int Kcat, unsigned short* __restrict__ WTh, unsigned short* __restrict__ WTl){
  int idx = blockIdx.x*256 + threadIdx.x;
  if (idx >= Kcat*128) return;
  int c = idx & 127, k = idx >> 7;
  float w = (k < Kx) ? Wr[k*128 + c] : Wn[(k - Kx)*128 + c];
  __hip_bfloat16 h = __float2bfloat16(w);
  float hf = __bfloat162float(h);
  __hip_bfloat16 l = __float2bfloat16(w - hf);
  WTh[(size_t)c*Kcat + k] = reinterpret_cast<unsigned short&>(h);
  WTl[(size_t)c*Kcat + k] = reinterpret_cast<unsigned short&>(l);
}

// ---------------- conv via bf16x3 MFMA: y = relu((scale.x)@Wr + agg@Wn + b), score = y.p ----
// 128x128 tile, 256 threads = 2x2 waves of 64x64, mfma_f32_16x16x32_bf16, split product
// Xh*Wh + Xh*Wl + Xl*Wh. X rows scaled by scaleX[row] (tanh-fold) during self-term staging.
// NOTE: yout aliases aggb: staging reads of a block's own rows all complete
// before the last barrier; epilogue writes after.

__global__ __launch_bounds__(256, 2) void conv_kernel(const float* __restrict__ xsrc, int strideX, int ntx,
      const float* aggb, int nta,
      const unsigned short* __restrict__ WTh, const unsigned short* __restrict__ WTl, int Kcat,
      const float* __restrict__ bias, const float* __restrict__ p, const float* __restrict__ scaleX,
      float* yout, float* __restrict__ score){
  __shared__ unsigned short XhL[128*32], XlL[128*32];
  __shared__ unsigned short WhL[128*32], WlL[128*32];
  __shared__ float sbuf[128*2];
  const int tid = threadIdx.x;
  const int row0 = blockIdx.x * 128;
  const int srow = tid & 127;          // staging row (X) / col (W)
  const int shalf = tid >> 7;          // staging k-half (16 k each)
  const int lane = tid & 63;
  const int wid = tid >> 6;            // 4 waves: 2x2
  const int wr = wid >> 1, wc = wid & 1;
  const int l15 = lane & 15, lkq = lane >> 4;

  const float xscale = scaleX ? scaleX[row0 + srow] : 1.f;

  f32x4 acc[4][4];
  #pragma unroll
  for (int m = 0; m < 4; ++m)
    #pragma unroll
    for (int j = 0; j < 4; ++j)
      acc[m][j] = (f32x4){0.f, 0.f, 0.f, 0.f};

  const int nt = ntx + nta;
  for (int t = 0; t < nt; ++t){
    __syncthreads();                   // previous tile's compute done
    // ---- stage X (fp32 -> scale -> bf16 hi/lo) ----
    {
      const float* Xs   = (t < ntx) ? xsrc : aggb;
      const int stride  = (t < ntx) ? strideX : 128;
      const int kc      = (t < ntx) ? t*32 : (t - ntx)*32;
      const float sc    = (t < ntx) ? xscale : 1.f;
      #pragma unroll
      for (int kq2 = 0; kq2 < 2; ++kq2){
        const int kq = shalf*2 + kq2;
        const float* xp = Xs + (size_t)(row0 + srow)*stride + kc + kq*8;
        float4 v0 = *(const float4*)(xp);
        float4 v1 = *(const float4*)(xp + 4);
        float vv[8] = {v0.x*sc, v0.y*sc, v0.z*sc, v0.w*sc,
                       v1.x*sc, v1.y*sc, v1.z*sc, v1.w*sc};
        short8 hs, ls;
        #pragma unroll
        for (int q = 0; q < 8; ++q){
          __hip_bfloat16 h = __float2bfloat16(vv[q]);
          float hf = __bfloat162float(h);
          __hip_bfloat16 lo = __float2bfloat16(vv[q] - hf);
          hs[q] = reinterpret_cast<short&>(h);
          ls[q] = reinterpret_cast<short&>(lo);
        }
        const int kqph = kq ^ (srow & 3);
        *(short8*)&XhL[srow*32 + kqph*8] = hs;
        *(short8*)&XlL[srow*32 + kqph*8] = ls;
      }
      // ---- stage W (already bf16 hi/lo, [col][k]) ----
      const int kcw = t*32;
      #pragma unroll
      for (int kq2 = 0; kq2 < 2; ++kq2){
        const int kq = shalf*2 + kq2;
        short8 h = *(const short8*)&WTh[(size_t)srow*Kcat + kcw + kq*8];
        short8 l = *(const short8*)&WTl[(size_t)srow*Kcat + kcw + kq*8];
        const int kqph = kq ^ (srow & 3);
        *(short8*)&WhL[srow*32 + kqph*8] = h;
        *(short8*)&WlL[srow*32 + kqph*8] = l;
      }
    }
    __syncthreads();
    // ---- MFMA: wave (wr,wc) computes rows wr*64..+63 x cols wc*64..+63 ----
    short8 bh[4], bl[4];
    #pragma unroll
    for (int j = 0; j < 4; ++j){
      const int col = wc*64 + j*16 + l15;
      const int offb = col*32 + (lkq ^ (col & 3))*8;
      bh[j] = *(const short8*)&WhL[offb];
      bl[j] = *(const short8*)&WlL[offb];
    }
    #pragma unroll
    for (int m = 0; m < 4; ++m){
      const int row = wr*64 + m*16 + l15;
      const int offa = row*32 + (lkq ^ (row & 3))*8;
      short8 ah = *(const short8*)&XhL[offa];
      short8 al = *(const short8*)&XlL[offa];
      #pragma unroll
      for (int j = 0; j < 4; ++j){
        acc[m][j] = __builtin_amdgcn_mfma_f32_16x16x32_bf16(ah, bh[j], acc[m][j], 0, 0, 0);
        acc[m][j] = __builtin_amdgcn_mfma_f32_16x16x32_bf16(ah, bl[j], acc[m][j], 0, 0, 0);
        acc[m][j] = __builtin_amdgcn_mfma_f32_16x16x32_bf16(al, bh[j], acc[m][j], 0, 0, 0);
      }
    }
  }

  // ---- epilogue: relu + bias, store y, fused score partials ----
  #pragma unroll
  for (int m = 0; m < 4; ++m){
    float prt[4] = {0.f, 0.f, 0.f, 0.f};
    #pragma unroll
    for (int j = 0; j < 4; ++j){
      const int col = wc*64 + j*16 + l15;
      const float bcol = bias[col];
      const float pcol = p[col];
      f32x4 a = acc[m][j];
      #pragma unroll
      for (int r = 0; r < 4; ++r){
        const int row = wr*64 + m*16 + lkq*4 + r;
        float y = fmaxf(a[r] + bcol, 0.f);
        yout[(size_t)(row0 + row)*128 + col] = y;
        prt[r] = fmaf(y, pcol, prt[r]);
      }
    }
    #pragma unroll
    for (int r = 0; r < 4; ++r){
      #pragma unroll
      for (int msk = 8; msk >= 1; msk >>= 1) prt[r] += __shfl_xor(prt[r], msk);
      if (l15 == 0) sbuf[(wr*64 + m*16 + lkq*4 + r)*2 + wc] = prt[r];
    }
  }
  __syncthreads();
  if (tid < 128) score[row0 + tid] = sbuf[tid*2] + sbuf[tid*2 + 1];
}

// ---------------- per-graph top-k via hybrid bitonic sort (raw score desc, idx asc) ----------------
// registers + shfl_xor for strides<64, LDS exchange only for strides>=64.
// Writes alive_next and scale (tanh for selected, 0 otherwise).

__global__ __launch_bounds__(1024) void topk_kernel(const float* __restrict__ score, const int* __restrict__ alive_cur,
      int* __restrict__ alive_next, float* __restrict__ scale, const float* __restrict__ p, int m){
  __shared__ float lv[1024];
  __shared__ int   li[1024];
  __shared__ float rnorm;
  const int g = blockIdx.x, t = threadIdx.x;
  if (t < 64){
    float v0 = p[t], v1 = p[t + 64];
    float ss = v0*v0 + v1*v1;
    #pragma unroll
    for (int mm = 32; mm >= 1; mm >>= 1) ss += __shfl_xor(ss, mm);
    if (t == 0) rnorm = rsqrtf(ss);
  }
  const int node = g*NPER + t;
  bool ok = alive_cur ? (alive_cur[node] != 0) : true;
  float v = ok ? score[node] : -INFINITY;
  int idx = node;
  alive_next[node] = 0;
  scale[node] = 0.f;

  auto cex_shfl = [&](int stride, bool dirUp){
    float vj = __shfl_xor(v, stride);
    int   ij = __shfl_xor(idx, stride);
    bool iAmLow = (t & stride) == 0;
    bool mineFirst = (v > vj) || (v == vj && idx < ij);   // desc score, asc idx
    bool takeMine = ((dirUp == iAmLow) == mineFirst);
    v   = takeMine ? v   : vj;
    idx = takeMine ? idx : ij;
  };
  auto cex_lds = [&](int stride, bool dirUp){
    __syncthreads();
    lv[t] = v; li[t] = idx;
    __syncthreads();
    float vj = lv[t ^ stride];
    int   ij = li[t ^ stride];
    bool iAmLow = (t & stride) == 0;
    bool mineFirst = (v > vj) || (v == vj && idx < ij);
    bool takeMine = ((dirUp == iAmLow) == mineFirst);
    v   = takeMine ? v   : vj;
    idx = takeMine ? idx : ij;
  };

  #pragma unroll
  for (int size = 2; size <= 64; size <<= 1){
    const bool dirUp = (t & size) == 0;
    for (int stride = size >> 1; stride >= 1; stride >>= 1)
      cex_shfl(stride, dirUp);
  }
  #pragma unroll
  for (int size = 128; size <= 1024; size <<= 1){
    const bool dirUp = (t & size) == 0;
    for (int stride = size >> 1; stride >= 64; stride >>= 1)
      cex_lds(stride, dirUp);
    for (int stride = 32; stride >= 1; stride >>= 1)
      cex_shfl(stride, dirUp);
  }

  if (t < m){
    alive_next[idx] = 1;
    scale[idx] = tanhf(v * rnorm);
  }
}

// ---------------- readout: per-graph masked max + mean of y*scale, accumulated into h ----------------
// grid (NB, 8): 512 blocks (2/CU). 1024 threads = 64 node-groups x 16 features;
// each thread 16 nodes with 4 independent accumulator chains; LDS tree over groups.

__global__ __launch_bounds__(1024) void readout_kernel(const float* __restrict__ y,
      const int* __restrict__ alive, const float* __restrict__ scale,
      float* __restrict__ h, int m){
  __shared__ float smx[64][17];
  __shared__ float ssm[64][17];
  int g = blockIdx.x;
  int fq = blockIdx.y;       // 0..7
  int t = threadIdx.x;
  int c  = t >> 4;           // node group 0..63
  int lf = t & 15;           // feature within group of 16
  int f  = fq*16 + lf;
  int base = g*NPER;
  float mx[4] = {-INFINITY, -INFINITY, -INFINITY, -INFINITY};
  float sm[4] = {0.f, 0.f, 0.f, 0.f};
  #pragma unroll
  for (int i = 0; i < 16; i += 4){
    #pragma unroll
    for (int q = 0; q < 4; ++q){
      int node = base + c + (i + q)*64;
      int al = alive[node];
      float o = y[(size_t)node*128 + f] * scale[node];   // scale==0 for dead -> o=0
      mx[q] = al ? fmaxf(mx[q], o) : mx[q];
      sm[q] += o;
    }
  }
  float mxa = fmaxf(fmaxf(mx[0], mx[1]), fmaxf(mx[2], mx[3]));
  float sma = (sm[0] + sm[1]) + (sm[2] + sm[3]);
  smx[c][lf] = mxa; ssm[c][lf] = sma;
  __syncthreads();
  for (int s = 32; s > 0; s >>= 1){
    if (c < s){
      smx[c][lf] = fmaxf(smx[c][lf], smx[c+s][lf]);
      ssm[c][lf] += ssm[c+s][lf];
    }
    __syncthreads();
  }
  if (c == 0){
    h[g*256 + f]       += smx[0][lf];
    h[g*256 + 128 + f] += ssm[0][lf] / (float)m;
  }
}

// ---------------- final MLP + log_softmax ----------------

__global__ __launch_bounds__(128) void final_kernel(const float* __restrict__ h,
      const float* __restrict__ l1w, const float* __restrict__ l1b,
      const float* __restrict__ l2w, const float* __restrict__ l2b,
      float* __restrict__ out){
  int g = blockIdx.x, t = threadIdx.x;
  __shared__ float hrow[256];
  __shared__ float red0[128], red1[128];
  hrow[t]       = h[g*256 + t];
  hrow[t + 128] = h[g*256 + 128 + t];
  __syncthreads();
  float a = l1b[t];
  for (int k = 0; k < 256; ++k) a = fmaf(hrow[k], l1w[k*128 + t], a);
  a = fmaxf(a, 0.f);
  red0[t] = a * l2w[t*2 + 0];
  red1[t] = a * l2w[t*2 + 1];
  __syncthreads();
  for (int s = 64; s > 0; s >>= 1){
    if (t < s){ red0[t] += red0[t + s]; red1[t] += red1[t + s]; }
    __syncthreads();
  }
  if (t == 0){
    float z0 = fmaxf(red0[0] + l2b[0], 0.f);
    float z1 = fmaxf(red1[0] + l2b[1], 0.f);
    float mz = fmaxf(z0, z1);
    float lse = mz + logf(expf(z0 - mz) + expf(z1 - mz));
    out[g*2 + 0] = z0 - lse;
    out[g*2 + 1] = z1 - lse;
  }
}

// ---------------- host ----------------

static inline size_t alignup(size_t x){ return (x + 255) & ~(size_t)255; }

extern "C" void kernel_launch(void* const* d_in, const int* in_sizes, int n_in,
                              void* d_out, int out_size, void* d_ws, size_t ws_size,
                              hipStream_t stream) {
  const float* x_in = (const float*)d_in[0];
  const int*   ei   = (const int*)d_in[1];
  const float* Wr[3] = {(const float*)d_in[3], (const float*)d_in[6], (const float*)d_in[9]};
  const float* Wn[3] = {(const float*)d_in[4], (const float*)d_in[7], (const float*)d_in[10]};
  const float* bs[3] = {(const float*)d_in[5], (const float*)d_in[8], (const float*)d_in[11]};
  const float* ps[3] = {(const float*)d_in[12], (const float*)d_in[13], (const float*)d_in[14]};
  const float* l1w = (const float*)d_in[15];
  const float* l1b = (const float*)d_in[16];
  const float* l2w = (const float*)d_in[17];
  const float* l2b = (const float*)d_in[18];
  float* out = (float*)d_out;

  char* w = (char*)d_ws;
  size_t o = 0;
  auto take = [&](size_t bytes) -> void* { void* p = w + o; o = alignup(o + bytes); return p; };
  int*   off    = (int*)  take((size_t)(NN + 1) * 4);
  int*   adj    = (int*)  take((size_t)NE * 4);
  int*   adj2   = (int*)  take((size_t)NE * 4);
  float* scl2   = (float*)take((size_t)NE * 4);
  int*   deg2   = (int*)  take((size_t)NN * 4);
  int*   cnt    = (int*)  take((size_t)NN * 4);
  int*   loc    = (int*)  take((size_t)NN * 4);
  int*   cursor = (int*)  take((size_t)NN * 4);
  int*   bsum   = (int*)  take(64 * 4);
  int*   boff   = (int*)  take(64 * 4);
  int*   aliveA = (int*)  take((size_t)NN * 4);
  int*   aliveB = (int*)  take((size_t)NN * 4);
  float* scale  = (float*)take((size_t)NN * 4);
  float* score  = (float*)take((size_t)NN * 4);
  float* h      = (float*)take((size_t)NB * 256 * 4);
  unsigned short* WTh = (unsigned short*)take((size_t)128 * 256 * 2);
  unsigned short* WTl = (unsigned short*)take((size_t)128 * 256 * 2);
  float* A      = (float*)take((size_t)NN * 128 * 4);  // y buffer (odd levels)
  float* Bb     = (float*)take((size_t)NN * 128 * 4);  // y buffer (even levels)
  (void)ws_size; (void)n_in; (void)in_sizes; (void)out_size;

  // CSR build (by dst, storing src)
  hipMemsetAsync(cnt, 0, (size_t)NN * 4, stream);
  count_kernel<<<NE/256, 256, 0, stream>>>(ei, cnt);
  scan1_kernel<<<NN/1024, 1024, 0, stream>>>(cnt, loc, bsum);
  scan2_kernel<<<1, 64, 0, stream>>>(bsum, boff);
  scan3_kernel<<<NN/1024, 1024, 0, stream>>>(loc, boff, off, cursor);
  fill_kernel<<<NE/256, 256, 0, stream>>>(ei, cursor, adj);
  hipMemsetAsync(h, 0, (size_t)NB * 256 * 4, stream);

  const int MS[3] = {820, 656, 525};
  int* aliveCur = nullptr;
  int* aliveNext = aliveA;
  float* bufs[2] = {Bb, A};      // y_l lives in bufs[l&1]
  for (int l = 0; l < 3; ++l){
    const int Kx = (l == 0) ? 64 : 128;
    const int Ka = (l == 0) ? 64 : 128;
    const int Kcat = Kx + Ka;
    float* aggb = bufs[l & 1];               // gather dst + conv yout (aliased by design)
    wsplit_kernel<<<(Kcat*128 + 255)/256, 256, 0, stream>>>(Wr[l], Wn[l], Kx, Kcat, WTh, WTl);
    if (l == 0){
      gather_kernel<<<NN*64/256, 256, 0, stream>>>(x_in, 64, 64, off, adj, nullptr, nullptr, aggb, nullptr);
      conv_kernel<<<NN/128, 256, 0, stream>>>(x_in, 64, Kx/32, aggb, Ka/32, WTh, WTl, Kcat,
                                              bs[0], ps[0], nullptr, aggb, score);
    } else {
      const float* ysrc = bufs[(l - 1) & 1]; // previous level's y
      compact_kernel<<<NN*64/256, 256, 0, stream>>>(off, adj, scale, aliveCur, adj2, scl2, deg2);
      gather_kernel<<<NN*64/256, 256, 0, stream>>>(ysrc, 128, 128, off, adj2, scl2, deg2, aggb, aliveCur);
      conv_kernel<<<NN/128, 256, 0, stream>>>(ysrc, 128, Kx/32, aggb, Ka/32, WTh, WTl, Kcat,
                                              bs[l], ps[l], scale, aggb, score);
    }
    topk_kernel<<<NB, 1024, 0, stream>>>(score, aliveCur, aliveNext, scale, ps[l], MS[l]);
    readout_kernel<<<dim3(NB, 8), 1024, 0, stream>>>(aggb, aliveNext, scale, h, MS[l]);
    aliveCur = aliveNext;
    aliveNext = (l == 0) ? aliveB : aliveA;
  }
  final_kernel<<<NB, 128, 0, stream>>>(h, l1w, l1b, l2w, l2b, out);
}